// Round 1
// baseline (1060.546 us; speedup 1.0000x reference)
//
#include <hip/hip_runtime.h>

#define N_NODES 200000
#define N_EDGES 800000
#define IN_DIM 768
#define HID 128
#define NG 1024

#define BM 128
#define BK 32

// ---------------- degree / norm ----------------
__global__ __launch_bounds__(256) void k_deg(const int* __restrict__ col, int* __restrict__ deg) {
  int e = blockIdx.x * 256 + threadIdx.x;
  if (e < N_EDGES) atomicAdd(&deg[col[e]], 1);
}

__global__ __launch_bounds__(256) void k_dinv(const int* __restrict__ deg, float* __restrict__ dinv) {
  int i = blockIdx.x * 256 + threadIdx.x;
  if (i < N_NODES) dinv[i] = rsqrtf((float)(deg[i] + 1)); // +1 = self loop; always >0
}

// ---------------- h = x @ W_conv  (fp32, 128x128 tile, 8x8/thread) ----------------
__global__ __launch_bounds__(256) void k_gemm_conv(const float* __restrict__ x,
                                                   const float* __restrict__ W,
                                                   float* __restrict__ h) {
  __shared__ float xs[BK][BM + 4];   // transposed x tile: xs[k][m], +4 pad keeps 16B align
  __shared__ float wsm[BK][HID];
  const int t = threadIdx.x;
  const int ty = t >> 4, tx = t & 15;
  const int bm = blockIdx.x * BM;
  float acc[8][8];
#pragma unroll
  for (int i = 0; i < 8; ++i)
#pragma unroll
    for (int j = 0; j < 8; ++j) acc[i][j] = 0.f;

  for (int k0 = 0; k0 < IN_DIM; k0 += BK) {
    // stage x tile transposed: 128 rows x 32 k; thread loads 16 contiguous floats
    {
      const int r = t >> 1;
      const int cb = (t & 1) * 16;
      const int grow = bm + r;
      float4 v[4];
      if (grow < N_NODES) {
        const float4* src = (const float4*)(x + (size_t)grow * IN_DIM + k0 + cb);
        v[0] = src[0]; v[1] = src[1]; v[2] = src[2]; v[3] = src[3];
      } else {
        float4 z = {0.f, 0.f, 0.f, 0.f};
        v[0] = z; v[1] = z; v[2] = z; v[3] = z;
      }
#pragma unroll
      for (int q = 0; q < 4; ++q) {
        xs[cb + q * 4 + 0][r] = v[q].x;
        xs[cb + q * 4 + 1][r] = v[q].y;
        xs[cb + q * 4 + 2][r] = v[q].z;
        xs[cb + q * 4 + 3][r] = v[q].w;
      }
    }
    // stage W tile: 32 k-rows x 128 cols
    {
      const int r = t >> 3;
      const int c = (t & 7) * 16;
      const float4* src = (const float4*)(W + (size_t)(k0 + r) * HID + c);
      float4* dst = (float4*)&wsm[r][c];
      dst[0] = src[0]; dst[1] = src[1]; dst[2] = src[2]; dst[3] = src[3];
    }
    __syncthreads();
#pragma unroll 8
    for (int kk = 0; kk < BK; ++kk) {
      float4 a0 = *(const float4*)&xs[kk][ty * 8];
      float4 a1 = *(const float4*)&xs[kk][ty * 8 + 4];
      float4 b0 = *(const float4*)&wsm[kk][tx * 8];
      float4 b1 = *(const float4*)&wsm[kk][tx * 8 + 4];
      float a[8] = {a0.x, a0.y, a0.z, a0.w, a1.x, a1.y, a1.z, a1.w};
      float b[8] = {b0.x, b0.y, b0.z, b0.w, b1.x, b1.y, b1.z, b1.w};
#pragma unroll
      for (int i = 0; i < 8; ++i)
#pragma unroll
        for (int j = 0; j < 8; ++j)
          acc[i][j] = fmaf(a[i], b[j], acc[i][j]);
    }
    __syncthreads();
  }
#pragma unroll
  for (int i = 0; i < 8; ++i) {
    int grow = bm + ty * 8 + i;
    if (grow < N_NODES) {
      float4 s0 = {acc[i][0], acc[i][1], acc[i][2], acc[i][3]};
      float4 s1 = {acc[i][4], acc[i][5], acc[i][6], acc[i][7]};
      float4* dst = (float4*)(h + (size_t)grow * HID + tx * 8);
      dst[0] = s0; dst[1] = s1;
    }
  }
}

// ---------------- edge scatter: acc[col] += h[row] * dinv[row]*dinv[col] ----------------
__global__ __launch_bounds__(256) void k_scatter(const int* __restrict__ row,
                                                 const int* __restrict__ col,
                                                 const float* __restrict__ dinv,
                                                 const float* __restrict__ h,
                                                 float* __restrict__ acc) {
  int gid = blockIdx.x * 256 + threadIdx.x;
  int e = gid >> 6;        // one wave (64 lanes) per edge
  int lane = gid & 63;
  if (e >= N_EDGES) return;
  int r = row[e], c = col[e];
  float w = dinv[r] * dinv[c];
  const float* hr = h + (size_t)r * HID;
  float* ac = acc + (size_t)c * HID;
  atomicAdd(&ac[lane], hr[lane] * w);
  atomicAdd(&ac[lane + 64], hr[lane + 64] * w);
}

// ---------------- self loop + bias + relu + global max pool ----------------
__global__ __launch_bounds__(256) void k_pool(const float* __restrict__ h,
                                              const float* __restrict__ acc,
                                              const float* __restrict__ dinv,
                                              const float* __restrict__ b_conv,
                                              const int* __restrict__ batch,
                                              unsigned* __restrict__ pooled) {
  int gid = blockIdx.x * 256 + threadIdx.x;
  int i = gid >> 7;
  int f = gid & 127;
  if (i >= N_NODES) return;
  float d = dinv[i];
  float v = acc[(size_t)i * HID + f] + h[(size_t)i * HID + f] * d * d + b_conv[f];
  v = fmaxf(v, 0.f);
  // relu output >= 0, so uint compare == float compare; pooled zero-initialized
  atomicMax(&pooled[(size_t)batch[i] * HID + f], __float_as_uint(v));
}

// ---------------- idx0 = searchsorted(batch, arange(NG)) ----------------
__global__ __launch_bounds__(256) void k_idx0(const int* __restrict__ batch, int* __restrict__ idx0) {
  int g = blockIdx.x * 256 + threadIdx.x;
  if (g >= NG) return;
  int lo = 0, hi = N_NODES;
  while (lo < hi) {
    int mid = (lo + hi) >> 1;
    if (batch[mid] < g) lo = mid + 1; else hi = mid;
  }
  idx0[g] = lo < N_NODES ? lo : N_NODES - 1;
}

// ---------------- news = relu(x[idx0] @ W0 + b0) ----------------
__global__ __launch_bounds__(128) void k_news(const float* __restrict__ x,
                                              const int* __restrict__ idx0,
                                              const float* __restrict__ W0,
                                              const float* __restrict__ b0,
                                              float* __restrict__ news) {
  __shared__ float xr[IN_DIM];
  int g = blockIdx.x;
  int f = threadIdx.x;
  const float* xp = x + (size_t)idx0[g] * IN_DIM;
  for (int k = f; k < IN_DIM; k += 128) xr[k] = xp[k];
  __syncthreads();
  float a = b0[f];
#pragma unroll 8
  for (int k = 0; k < IN_DIM; ++k) a = fmaf(xr[k], W0[(size_t)k * HID + f], a);
  news[(size_t)g * HID + f] = fmaxf(a, 0.f);
}

// ---------------- z1 = relu([pooled, news] @ W1 + b1) ----------------
__global__ __launch_bounds__(128) void k_hidden(const float* __restrict__ pooled,
                                                const float* __restrict__ news,
                                                const float* __restrict__ W1,
                                                const float* __restrict__ b1,
                                                float* __restrict__ z1) {
  __shared__ float zr[2 * HID];
  int g = blockIdx.x;
  int f = threadIdx.x;
  zr[f] = pooled[(size_t)g * HID + f];
  zr[HID + f] = news[(size_t)g * HID + f];
  __syncthreads();
  float a = b1[f];
#pragma unroll 8
  for (int k = 0; k < 2 * HID; ++k) a = fmaf(zr[k], W1[(size_t)k * HID + f], a);
  z1[(size_t)g * HID + f] = fmaxf(a, 0.f);
}

// ---------------- logits + log_softmax ----------------
__global__ __launch_bounds__(256) void k_out(const float* __restrict__ z1,
                                             const float* __restrict__ W2,
                                             const float* __restrict__ b2,
                                             float* __restrict__ out) {
  int g = blockIdx.x * 256 + threadIdx.x;
  if (g >= NG) return;
  float l0 = b2[0], l1 = b2[1];
#pragma unroll 8
  for (int k = 0; k < HID; ++k) {
    float z = z1[(size_t)g * HID + k];
    l0 = fmaf(z, W2[k * 2 + 0], l0);
    l1 = fmaf(z, W2[k * 2 + 1], l1);
  }
  float m = fmaxf(l0, l1);
  float lse = m + logf(expf(l0 - m) + expf(l1 - m));
  out[g * 2 + 0] = l0 - lse;
  out[g * 2 + 1] = l1 - lse;
}

extern "C" void kernel_launch(void* const* d_in, const int* in_sizes, int n_in,
                              void* d_out, int out_size, void* d_ws, size_t ws_size,
                              hipStream_t stream) {
  const float* x      = (const float*)d_in[0];
  const int* edge     = (const int*)d_in[1];
  const int* batch    = (const int*)d_in[2];
  const float* W_conv = (const float*)d_in[4];
  const float* b_conv = (const float*)d_in[5];
  const float* W0     = (const float*)d_in[6];
  const float* b0     = (const float*)d_in[7];
  const float* W1     = (const float*)d_in[8];
  const float* b1     = (const float*)d_in[9];
  const float* W2     = (const float*)d_in[10];
  const float* b2     = (const float*)d_in[11];
  float* out = (float*)d_out;

  const int* row = edge;
  const int* col = edge + N_EDGES;

  // workspace layout (bytes)
  char* ws = (char*)d_ws;
  float*    h      = (float*)(ws);                               // 102,400,000
  float*    acc    = (float*)(ws + 102400000);                   // 102,400,000
  int*      deg    = (int*)  (ws + 204800000);                   //     800,000
  float*    dinv   = (float*)(ws + 205600000);                   //     800,000
  unsigned* pooled = (unsigned*)(ws + 206400000);                //     524,288
  float*    news   = (float*)(ws + 206924288);                   //     524,288
  float*    z1     = (float*)(ws + 207448576);                   //     524,288
  int*      idx0   = (int*)  (ws + 207972864);                   //       4,096

  // zero-init accumulators (every call: ws is not re-poisoned, but must be deterministic)
  hipMemsetAsync(acc, 0, (size_t)N_NODES * HID * sizeof(float), stream);
  hipMemsetAsync(deg, 0, (size_t)N_NODES * sizeof(int), stream);
  hipMemsetAsync(pooled, 0, (size_t)NG * HID * sizeof(unsigned), stream);

  k_deg<<<(N_EDGES + 255) / 256, 256, 0, stream>>>(col, deg);
  k_dinv<<<(N_NODES + 255) / 256, 256, 0, stream>>>(deg, dinv);
  k_gemm_conv<<<(N_NODES + BM - 1) / BM, 256, 0, stream>>>(x, W_conv, h);
  k_scatter<<<(N_EDGES * 64 + 255) / 256, 256, 0, stream>>>(row, col, dinv, h, acc);
  k_pool<<<((size_t)N_NODES * HID + 255) / 256, 256, 0, stream>>>(h, acc, dinv, b_conv, batch, pooled);
  k_idx0<<<(NG + 255) / 256, 256, 0, stream>>>(batch, idx0);
  k_news<<<NG, 128, 0, stream>>>(x, idx0, W0, b0, news);
  k_hidden<<<NG, 128, 0, stream>>>((const float*)pooled, news, W1, b1, z1);
  k_out<<<(NG + 255) / 256, 256, 0, stream>>>(z1, W2, b2, out);
}

// Round 2
// 781.277 us; speedup vs baseline: 1.3575x; 1.3575x over previous
//
#include <hip/hip_runtime.h>

#define N_NODES 200000
#define N_EDGES 800000
#define IN_DIM 768
#define HID 128
#define NG 1024

// MFMA GEMM tile
#define BM 128
#define BK 64
#define LDS_STRIDE (BK + 8)   // 72 bf16 = 144 B row stride: 16B-aligned, ~2-way conflicts only

typedef short bf16x8 __attribute__((ext_vector_type(8)));
typedef float f32x4 __attribute__((ext_vector_type(4)));

__device__ inline unsigned short f2bf_rn(float f) {   // round-to-nearest-even bf16 (no NaN inputs here)
  unsigned u = __float_as_uint(f);
  return (unsigned short)((u + 0x7fffu + ((u >> 16) & 1u)) >> 16);
}
__device__ inline float bf2f(unsigned short s) { return __uint_as_float(((unsigned)s) << 16); }

// ---------------- degree / norm ----------------
__global__ __launch_bounds__(256) void k_deg(const int* __restrict__ col, int* __restrict__ deg) {
  int e = blockIdx.x * 256 + threadIdx.x;
  if (e < N_EDGES) atomicAdd(&deg[col[e]], 1);
}

// in-place: reads deg (int), writes dinv (float) to the SAME buffer
__global__ __launch_bounds__(256) void k_dinv(int* __restrict__ degdinv) {
  int i = blockIdx.x * 256 + threadIdx.x;
  if (i < N_NODES) {
    int d = degdinv[i];
    ((float*)degdinv)[i] = rsqrtf((float)(d + 1)); // +1 self loop; always > 0
  }
}

// ---------------- W_conv -> transposed split bf16 (once, tiny) ----------------
__global__ __launch_bounds__(256) void k_prepW(const float* __restrict__ W,
                                               unsigned short* __restrict__ WT_hi,
                                               unsigned short* __restrict__ WT_lo) {
  int i = blockIdx.x * 256 + threadIdx.x;
  if (i >= IN_DIM * HID) return;
  int k = i / HID, n = i % HID;
  float w = W[i];
  unsigned short hi = f2bf_rn(w);
  WT_hi[(size_t)n * IN_DIM + k] = hi;
  WT_lo[(size_t)n * IN_DIM + k] = f2bf_rn(w - bf2f(hi));
}

// ---------------- h = x @ W_conv via split-bf16 MFMA ----------------
// x fp32 [N,768]; WT_{hi,lo} bf16 [128,768] (transposed); h fp32 [N,128]
__global__ __launch_bounds__(256, 2) void k_gemm_mfma(const float* __restrict__ x,
                                                      const unsigned short* __restrict__ WT_hi,
                                                      const unsigned short* __restrict__ WT_lo,
                                                      float* __restrict__ h) {
  __shared__ unsigned short Ah[BM][LDS_STRIDE];
  __shared__ unsigned short Al[BM][LDS_STRIDE];
  __shared__ unsigned short Bh[HID][LDS_STRIDE];
  __shared__ unsigned short Bl[HID][LDS_STRIDE];

  const int t = threadIdx.x;
  const int lane = t & 63;
  const int wid = t >> 6;                 // wave 0..3 -> rows wid*32 .. +31
  const int bm = blockIdx.x * BM;

  f32x4 acc[2][8];
#pragma unroll
  for (int i = 0; i < 2; ++i)
#pragma unroll
    for (int j = 0; j < 8; ++j) acc[i][j] = (f32x4){0.f, 0.f, 0.f, 0.f};

  const int lr = lane & 15;               // A row / B col within 16-tile
  const int lk = (lane >> 4) * 8;         // k offset within 32

  for (int k0 = 0; k0 < IN_DIM; k0 += BK) {
    // ---- stage A: x[bm..bm+128)[k0..k0+64) -> split bf16, padded rows ----
    {
      int r = t >> 1;
      int kc = (t & 1) * 32;
      int grow = bm + r;
      float4 v[8];
      if (grow < N_NODES) {
        const float4* src = (const float4*)(x + (size_t)grow * IN_DIM + k0 + kc);
#pragma unroll
        for (int q = 0; q < 8; ++q) v[q] = src[q];
      } else {
        float4 z = {0.f, 0.f, 0.f, 0.f};
#pragma unroll
        for (int q = 0; q < 8; ++q) v[q] = z;
      }
      const float* vf = (const float*)v;
      unsigned short sh[32], sl[32];
#pragma unroll
      for (int q = 0; q < 32; ++q) {
        unsigned short hi = f2bf_rn(vf[q]);
        sh[q] = hi;
        sl[q] = f2bf_rn(vf[q] - bf2f(hi));
      }
#pragma unroll
      for (int q = 0; q < 4; ++q) {
        *(bf16x8*)&Ah[r][kc + q * 8] = *(const bf16x8*)&sh[q * 8];
        *(bf16x8*)&Al[r][kc + q * 8] = *(const bf16x8*)&sl[q * 8];
      }
    }
    // ---- stage B: WT_{hi,lo}[0..128)[k0..k0+64) ----
    {
      int n = t >> 1;
      int kc = (t & 1) * 32;
      const bf16x8* srch = (const bf16x8*)(WT_hi + (size_t)n * IN_DIM + k0 + kc);
      const bf16x8* srcl = (const bf16x8*)(WT_lo + (size_t)n * IN_DIM + k0 + kc);
#pragma unroll
      for (int q = 0; q < 4; ++q) {
        *(bf16x8*)&Bh[n][kc + q * 8] = srch[q];
        *(bf16x8*)&Bl[n][kc + q * 8] = srcl[q];
      }
    }
    __syncthreads();

#pragma unroll
    for (int ks = 0; ks < 2; ++ks) {
      const int kb = ks * 32 + lk;
      bf16x8 ah[2], al[2];
#pragma unroll
      for (int rt = 0; rt < 2; ++rt) {
        int row = wid * 32 + rt * 16 + lr;
        ah[rt] = *(const bf16x8*)&Ah[row][kb];
        al[rt] = *(const bf16x8*)&Al[row][kb];
      }
#pragma unroll
      for (int ct = 0; ct < 8; ++ct) {
        bf16x8 bh = *(const bf16x8*)&Bh[ct * 16 + lr][kb];
        bf16x8 bl = *(const bf16x8*)&Bl[ct * 16 + lr][kb];
#pragma unroll
        for (int rt = 0; rt < 2; ++rt) {
          acc[rt][ct] = __builtin_amdgcn_mfma_f32_16x16x32_bf16(ah[rt], bh, acc[rt][ct], 0, 0, 0);
          acc[rt][ct] = __builtin_amdgcn_mfma_f32_16x16x32_bf16(al[rt], bh, acc[rt][ct], 0, 0, 0);
          acc[rt][ct] = __builtin_amdgcn_mfma_f32_16x16x32_bf16(ah[rt], bl, acc[rt][ct], 0, 0, 0);
        }
      }
    }
    __syncthreads();
  }

  // epilogue: D row = (lane>>4)*4 + j, col = lane&15  (m89-verified layout)
  const int dcol = lane & 15;
  const int drow = (lane >> 4) * 4;
#pragma unroll
  for (int rt = 0; rt < 2; ++rt) {
#pragma unroll
    for (int j = 0; j < 4; ++j) {
      int grow = bm + wid * 32 + rt * 16 + drow + j;
      if (grow < N_NODES) {
        float* dst = h + (size_t)grow * HID;
#pragma unroll
        for (int ct = 0; ct < 8; ++ct) dst[ct * 16 + dcol] = acc[rt][ct][j];
      }
    }
  }
}

// ---------------- edge scatter: acc[col] += h[row] * dinv[row]*dinv[col] ----------------
__global__ __launch_bounds__(256) void k_scatter(const int* __restrict__ row,
                                                 const int* __restrict__ col,
                                                 const float* __restrict__ dinv,
                                                 const float* __restrict__ h,
                                                 float* __restrict__ acc) {
  int gid = blockIdx.x * 256 + threadIdx.x;
  int e = gid >> 6;        // one wave per edge
  int lane = gid & 63;
  if (e >= N_EDGES) return;
  int r = row[e], c = col[e];
  float w = dinv[r] * dinv[c];
  const float* hr = h + (size_t)r * HID;
  float* ac = acc + (size_t)c * HID;
  atomicAdd(&ac[lane], hr[lane] * w);
  atomicAdd(&ac[lane + 64], hr[lane + 64] * w);
}

// ---------------- self loop + bias + relu + global max pool ----------------
__global__ __launch_bounds__(256) void k_pool(const float* __restrict__ h,
                                              const float* __restrict__ acc,
                                              const float* __restrict__ dinv,
                                              const float* __restrict__ b_conv,
                                              const int* __restrict__ batch,
                                              unsigned* __restrict__ pooled) {
  int gid = blockIdx.x * 256 + threadIdx.x;
  int i = gid >> 7;
  int f = gid & 127;
  if (i >= N_NODES) return;
  float d = dinv[i];
  float v = acc[(size_t)i * HID + f] + h[(size_t)i * HID + f] * d * d + b_conv[f];
  v = fmaxf(v, 0.f);
  atomicMax(&pooled[(size_t)batch[i] * HID + f], __float_as_uint(v));
}

// ---------------- idx0 = searchsorted(batch, arange(NG)) ----------------
__global__ __launch_bounds__(256) void k_idx0(const int* __restrict__ batch, int* __restrict__ idx0) {
  int g = blockIdx.x * 256 + threadIdx.x;
  if (g >= NG) return;
  int lo = 0, hi = N_NODES;
  while (lo < hi) {
    int mid = (lo + hi) >> 1;
    if (batch[mid] < g) lo = mid + 1; else hi = mid;
  }
  idx0[g] = lo < N_NODES ? lo : N_NODES - 1;
}

// ---------------- news = relu(x[idx0] @ W0 + b0) ----------------
__global__ __launch_bounds__(128) void k_news(const float* __restrict__ x,
                                              const int* __restrict__ idx0,
                                              const float* __restrict__ W0,
                                              const float* __restrict__ b0,
                                              float* __restrict__ news) {
  __shared__ float xr[IN_DIM];
  int g = blockIdx.x;
  int f = threadIdx.x;
  const float* xp = x + (size_t)idx0[g] * IN_DIM;
  for (int k = f; k < IN_DIM; k += 128) xr[k] = xp[k];
  __syncthreads();
  float a = b0[f];
#pragma unroll 8
  for (int k = 0; k < IN_DIM; ++k) a = fmaf(xr[k], W0[(size_t)k * HID + f], a);
  news[(size_t)g * HID + f] = fmaxf(a, 0.f);
}

// ---------------- z1 = relu([pooled, news] @ W1 + b1) ----------------
__global__ __launch_bounds__(128) void k_hidden(const float* __restrict__ pooled,
                                                const float* __restrict__ news,
                                                const float* __restrict__ W1,
                                                const float* __restrict__ b1,
                                                float* __restrict__ z1) {
  __shared__ float zr[2 * HID];
  int g = blockIdx.x;
  int f = threadIdx.x;
  zr[f] = pooled[(size_t)g * HID + f];
  zr[HID + f] = news[(size_t)g * HID + f];
  __syncthreads();
  float a = b1[f];
#pragma unroll 8
  for (int k = 0; k < 2 * HID; ++k) a = fmaf(zr[k], W1[(size_t)k * HID + f], a);
  z1[(size_t)g * HID + f] = fmaxf(a, 0.f);
}

// ---------------- logits + log_softmax ----------------
__global__ __launch_bounds__(256) void k_out(const float* __restrict__ z1,
                                             const float* __restrict__ W2,
                                             const float* __restrict__ b2,
                                             float* __restrict__ out) {
  int g = blockIdx.x * 256 + threadIdx.x;
  if (g >= NG) return;
  float l0 = b2[0], l1 = b2[1];
#pragma unroll 8
  for (int k = 0; k < HID; ++k) {
    float z = z1[(size_t)g * HID + k];
    l0 = fmaf(z, W2[k * 2 + 0], l0);
    l1 = fmaf(z, W2[k * 2 + 1], l1);
  }
  float m = fmaxf(l0, l1);
  float lse = m + logf(expf(l0 - m) + expf(l1 - m));
  out[g * 2 + 0] = l0 - lse;
  out[g * 2 + 1] = l1 - lse;
}

extern "C" void kernel_launch(void* const* d_in, const int* in_sizes, int n_in,
                              void* d_out, int out_size, void* d_ws, size_t ws_size,
                              hipStream_t stream) {
  const float* x      = (const float*)d_in[0];
  const int* edge     = (const int*)d_in[1];
  const int* batch    = (const int*)d_in[2];
  const float* W_conv = (const float*)d_in[4];
  const float* b_conv = (const float*)d_in[5];
  const float* W0     = (const float*)d_in[6];
  const float* b0     = (const float*)d_in[7];
  const float* W1     = (const float*)d_in[8];
  const float* b1     = (const float*)d_in[9];
  const float* W2     = (const float*)d_in[10];
  const float* b2     = (const float*)d_in[11];
  float* out = (float*)d_out;

  const int* row = edge;
  const int* col = edge + N_EDGES;

  // workspace layout (bytes) — stays within the 207.97 MB footprint proven in R1
  char* ws = (char*)d_ws;
  float*          h       = (float*)(ws);                        // 102,400,000
  float*          acc     = (float*)(ws + 102400000);            // 102,400,000
  int*            degdinv = (int*)  (ws + 204800000);            //     800,000 (int deg, then float dinv in place)
  unsigned short* WT_hi   = (unsigned short*)(ws + 205600000);   //     196,608
  unsigned short* WT_lo   = (unsigned short*)(ws + 205796608);   //     196,608
  unsigned*       pooled  = (unsigned*)(ws + 205993216);         //     524,288
  float*          news    = (float*)(ws + 206517504);            //     524,288
  float*          z1      = (float*)(ws + 207041792);            //     524,288
  int*            idx0    = (int*)  (ws + 207566080);            //       4,096

  hipMemsetAsync(acc, 0, (size_t)N_NODES * HID * sizeof(float), stream);
  hipMemsetAsync(degdinv, 0, (size_t)N_NODES * sizeof(int), stream);
  hipMemsetAsync(pooled, 0, (size_t)NG * HID * sizeof(unsigned), stream);

  k_deg<<<(N_EDGES + 255) / 256, 256, 0, stream>>>(col, degdinv);
  k_dinv<<<(N_NODES + 255) / 256, 256, 0, stream>>>(degdinv);
  k_prepW<<<(IN_DIM * HID + 255) / 256, 256, 0, stream>>>(W_conv, WT_hi, WT_lo);
  k_gemm_mfma<<<(N_NODES + BM - 1) / BM, 256, 0, stream>>>(x, WT_hi, WT_lo, h);
  k_scatter<<<((size_t)N_EDGES * 64 + 255) / 256, 256, 0, stream>>>(row, col, (const float*)degdinv, h, acc);
  k_pool<<<((size_t)N_NODES * HID + 255) / 256, 256, 0, stream>>>(h, acc, (const float*)degdinv, b_conv, batch, pooled);
  k_idx0<<<(NG + 255) / 256, 256, 0, stream>>>(batch, idx0);
  k_news<<<NG, 128, 0, stream>>>(x, idx0, W0, b0, news);
  k_hidden<<<NG, 128, 0, stream>>>((const float*)pooled, news, W1, b1, z1);
  k_out<<<(NG + 255) / 256, 256, 0, stream>>>(z1, W2, b2, out);
}

// Round 3
// 515.917 us; speedup vs baseline: 2.0557x; 1.5143x over previous
//
#include <hip/hip_runtime.h>

#define N_NODES 200000
#define N_EDGES 800000
#define IN_DIM 768
#define HID 128
#define NG 1024

// MFMA GEMM tile
#define BM 128
#define BK 64
#define LDS_STRIDE (BK + 8)   // 72 bf16 = 144 B row stride: 16B-aligned, ~2-way conflicts only

// scan
#define SCAN_B 1024
#define NSB ((N_NODES + SCAN_B - 1) / SCAN_B)   // 196

typedef short bf16x8 __attribute__((ext_vector_type(8)));
typedef float f32x4 __attribute__((ext_vector_type(4)));

__device__ inline unsigned short f2bf_rn(float f) {
  unsigned u = __float_as_uint(f);
  return (unsigned short)((u + 0x7fffu + ((u >> 16) & 1u)) >> 16);
}
__device__ inline float bf2f(unsigned short s) { return __uint_as_float(((unsigned)s) << 16); }

// ---------------- degree ----------------
__global__ __launch_bounds__(256) void k_deg(const int* __restrict__ col, int* __restrict__ deg) {
  int e = blockIdx.x * 256 + threadIdx.x;
  if (e < N_EDGES) atomicAdd(&deg[col[e]], 1);
}

__global__ __launch_bounds__(256) void k_dinv(const int* __restrict__ deg, float* __restrict__ dinv) {
  int i = blockIdx.x * 256 + threadIdx.x;
  if (i < N_NODES) dinv[i] = rsqrtf((float)(deg[i] + 1)); // +1 self loop
}

// ---------------- exclusive scan of deg -> start/cursor ----------------
__global__ __launch_bounds__(256) void k_scan1(const int* __restrict__ deg, int* __restrict__ bsum) {
  __shared__ int red[256];
  int b = blockIdx.x, t = threadIdx.x;
  int base = b * SCAN_B + t * 4;
  int s = 0;
#pragma unroll
  for (int q = 0; q < 4; ++q) { int idx = base + q; if (idx < N_NODES) s += deg[idx]; }
  red[t] = s; __syncthreads();
  for (int o = 128; o > 0; o >>= 1) { if (t < o) red[t] += red[t + o]; __syncthreads(); }
  if (t == 0) bsum[b] = red[0];
}

__global__ __launch_bounds__(256) void k_scan2(const int* __restrict__ bsum, int* __restrict__ boff) {
  __shared__ int s[256];
  int t = threadIdx.x;
  int v = (t < NSB) ? bsum[t] : 0;
  s[t] = v; __syncthreads();
  for (int o = 1; o < 256; o <<= 1) {
    int add = (t >= o) ? s[t - o] : 0;
    __syncthreads();
    s[t] += add;
    __syncthreads();
  }
  if (t < NSB) boff[t] = s[t] - v;  // exclusive
}

__global__ __launch_bounds__(256) void k_scan3(const int* __restrict__ deg, const int* __restrict__ boff,
                                               int* __restrict__ start, int* __restrict__ cursor) {
  __shared__ int s[256];
  int b = blockIdx.x, t = threadIdx.x;
  int base = b * SCAN_B + t * 4;
  int v[4]; int sum = 0;
#pragma unroll
  for (int q = 0; q < 4; ++q) { v[q] = (base + q < N_NODES) ? deg[base + q] : 0; sum += v[q]; }
  s[t] = sum; __syncthreads();
  int my = sum;
  for (int o = 1; o < 256; o <<= 1) {
    int add = (t >= o) ? s[t - o] : 0;
    __syncthreads();
    s[t] += add;
    __syncthreads();
  }
  int excl = s[t] - my + boff[b];
#pragma unroll
  for (int q = 0; q < 4; ++q) {
    int idx = base + q;
    if (idx < N_NODES) { start[idx] = excl; cursor[idx] = excl; excl += v[q]; }
  }
  if (b == 0 && t == 0) start[N_NODES] = N_EDGES;
}

// ---------------- bin edges into CSR ----------------
__global__ __launch_bounds__(256) void k_bin(const int* __restrict__ row, const int* __restrict__ col,
                                             int* __restrict__ cursor, int* __restrict__ srcs) {
  int e = blockIdx.x * 256 + threadIdx.x;
  if (e < N_EDGES) {
    int slot = atomicAdd(&cursor[col[e]], 1);
    srcs[slot] = row[e];
  }
}

// ---------------- W_conv -> transposed split bf16 ----------------
__global__ __launch_bounds__(256) void k_prepW(const float* __restrict__ W,
                                               unsigned short* __restrict__ WT_hi,
                                               unsigned short* __restrict__ WT_lo) {
  int i = blockIdx.x * 256 + threadIdx.x;
  if (i >= IN_DIM * HID) return;
  int k = i / HID, n = i % HID;
  float w = W[i];
  unsigned short hi = f2bf_rn(w);
  WT_hi[(size_t)n * IN_DIM + k] = hi;
  WT_lo[(size_t)n * IN_DIM + k] = f2bf_rn(w - bf2f(hi));
}

// ---------------- h = x @ W_conv via split-bf16 MFMA (unchanged from R2) ----------------
__global__ __launch_bounds__(256, 2) void k_gemm_mfma(const float* __restrict__ x,
                                                      const unsigned short* __restrict__ WT_hi,
                                                      const unsigned short* __restrict__ WT_lo,
                                                      float* __restrict__ h) {
  __shared__ unsigned short Ah[BM][LDS_STRIDE];
  __shared__ unsigned short Al[BM][LDS_STRIDE];
  __shared__ unsigned short Bh[HID][LDS_STRIDE];
  __shared__ unsigned short Bl[HID][LDS_STRIDE];

  const int t = threadIdx.x;
  const int lane = t & 63;
  const int wid = t >> 6;
  const int bm = blockIdx.x * BM;

  f32x4 acc[2][8];
#pragma unroll
  for (int i = 0; i < 2; ++i)
#pragma unroll
    for (int j = 0; j < 8; ++j) acc[i][j] = (f32x4){0.f, 0.f, 0.f, 0.f};

  const int lr = lane & 15;
  const int lk = (lane >> 4) * 8;

  for (int k0 = 0; k0 < IN_DIM; k0 += BK) {
    {
      int r = t >> 1;
      int kc = (t & 1) * 32;
      int grow = bm + r;
      float4 v[8];
      if (grow < N_NODES) {
        const float4* src = (const float4*)(x + (size_t)grow * IN_DIM + k0 + kc);
#pragma unroll
        for (int q = 0; q < 8; ++q) v[q] = src[q];
      } else {
        float4 z = {0.f, 0.f, 0.f, 0.f};
#pragma unroll
        for (int q = 0; q < 8; ++q) v[q] = z;
      }
      const float* vf = (const float*)v;
      unsigned short sh[32], sl[32];
#pragma unroll
      for (int q = 0; q < 32; ++q) {
        unsigned short hi = f2bf_rn(vf[q]);
        sh[q] = hi;
        sl[q] = f2bf_rn(vf[q] - bf2f(hi));
      }
#pragma unroll
      for (int q = 0; q < 4; ++q) {
        *(bf16x8*)&Ah[r][kc + q * 8] = *(const bf16x8*)&sh[q * 8];
        *(bf16x8*)&Al[r][kc + q * 8] = *(const bf16x8*)&sl[q * 8];
      }
    }
    {
      int n = t >> 1;
      int kc = (t & 1) * 32;
      const bf16x8* srch = (const bf16x8*)(WT_hi + (size_t)n * IN_DIM + k0 + kc);
      const bf16x8* srcl = (const bf16x8*)(WT_lo + (size_t)n * IN_DIM + k0 + kc);
#pragma unroll
      for (int q = 0; q < 4; ++q) {
        *(bf16x8*)&Bh[n][kc + q * 8] = srch[q];
        *(bf16x8*)&Bl[n][kc + q * 8] = srcl[q];
      }
    }
    __syncthreads();

#pragma unroll
    for (int ks = 0; ks < 2; ++ks) {
      const int kb = ks * 32 + lk;
      bf16x8 ah[2], al[2];
#pragma unroll
      for (int rt = 0; rt < 2; ++rt) {
        int rrow = wid * 32 + rt * 16 + lr;
        ah[rt] = *(const bf16x8*)&Ah[rrow][kb];
        al[rt] = *(const bf16x8*)&Al[rrow][kb];
      }
#pragma unroll
      for (int ct = 0; ct < 8; ++ct) {
        bf16x8 bh = *(const bf16x8*)&Bh[ct * 16 + lr][kb];
        bf16x8 bl = *(const bf16x8*)&Bl[ct * 16 + lr][kb];
#pragma unroll
        for (int rt = 0; rt < 2; ++rt) {
          acc[rt][ct] = __builtin_amdgcn_mfma_f32_16x16x32_bf16(ah[rt], bh, acc[rt][ct], 0, 0, 0);
          acc[rt][ct] = __builtin_amdgcn_mfma_f32_16x16x32_bf16(al[rt], bh, acc[rt][ct], 0, 0, 0);
          acc[rt][ct] = __builtin_amdgcn_mfma_f32_16x16x32_bf16(ah[rt], bl, acc[rt][ct], 0, 0, 0);
        }
      }
    }
    __syncthreads();
  }

  const int dcol = lane & 15;
  const int drow = (lane >> 4) * 4;
#pragma unroll
  for (int rt = 0; rt < 2; ++rt) {
#pragma unroll
    for (int j = 0; j < 4; ++j) {
      int grow = bm + wid * 32 + rt * 16 + drow + j;
      if (grow < N_NODES) {
        float* dst = h + (size_t)grow * HID;
#pragma unroll
        for (int ct = 0; ct < 8; ++ct) dst[ct * 16 + dcol] = acc[rt][ct][j];
      }
    }
  }
}

// ---------------- fused gather + self-loop + bias + relu + max-pool ----------------
// one wave per 4 consecutive nodes; lane owns features (lane, lane+64)
__global__ __launch_bounds__(256) void k_gather(const float* __restrict__ h,
                                                const float* __restrict__ dinv,
                                                const int* __restrict__ start,
                                                const int* __restrict__ srcs,
                                                const float* __restrict__ b_conv,
                                                const int* __restrict__ batch,
                                                unsigned* __restrict__ pooled) {
  int gid = blockIdx.x * 256 + threadIdx.x;
  int wv = gid >> 6, lane = gid & 63;
  int n0 = wv * 4;
  if (n0 >= N_NODES) return;
  float bc0 = b_conv[lane], bc1 = b_conv[lane + 64];
  int gcur = -1;
  float m0 = 0.f, m1 = 0.f;
  int nend = n0 + 4 < N_NODES ? n0 + 4 : N_NODES;
  for (int i = n0; i < nend; ++i) {
    float di = dinv[i];
    const float* hi_ = h + (size_t)i * HID;
    float sw = di * di;
    float a0 = hi_[lane] * sw;
    float a1 = hi_[lane + 64] * sw;
    int s = start[i], e = start[i + 1];
    for (int sl = s; sl < e; ++sl) {
      int src = srcs[sl];                 // wave-broadcast
      float w = dinv[src] * di;           // wave-broadcast
      const float* hs = h + (size_t)src * HID;
      a0 = fmaf(hs[lane], w, a0);
      a1 = fmaf(hs[lane + 64], w, a1);
    }
    a0 = fmaxf(a0 + bc0, 0.f);
    a1 = fmaxf(a1 + bc1, 0.f);
    int g = batch[i];
    if (g != gcur) {
      if (gcur >= 0) {
        atomicMax(&pooled[(size_t)gcur * HID + lane], __float_as_uint(m0));
        atomicMax(&pooled[(size_t)gcur * HID + lane + 64], __float_as_uint(m1));
      }
      gcur = g; m0 = a0; m1 = a1;
    } else {
      m0 = fmaxf(m0, a0);
      m1 = fmaxf(m1, a1);
    }
  }
  if (gcur >= 0) {
    atomicMax(&pooled[(size_t)gcur * HID + lane], __float_as_uint(m0));
    atomicMax(&pooled[(size_t)gcur * HID + lane + 64], __float_as_uint(m1));
  }
}

// ---------------- idx0 = searchsorted(batch, arange(NG)) ----------------
__global__ __launch_bounds__(256) void k_idx0(const int* __restrict__ batch, int* __restrict__ idx0) {
  int g = blockIdx.x * 256 + threadIdx.x;
  if (g >= NG) return;
  int lo = 0, hi = N_NODES;
  while (lo < hi) {
    int mid = (lo + hi) >> 1;
    if (batch[mid] < g) lo = mid + 1; else hi = mid;
  }
  idx0[g] = lo < N_NODES ? lo : N_NODES - 1;
}

// ---------------- news = relu(x[idx0] @ W0 + b0) ----------------
__global__ __launch_bounds__(128) void k_news(const float* __restrict__ x,
                                              const int* __restrict__ idx0,
                                              const float* __restrict__ W0,
                                              const float* __restrict__ b0,
                                              float* __restrict__ news) {
  __shared__ float xr[IN_DIM];
  int g = blockIdx.x;
  int f = threadIdx.x;
  const float* xp = x + (size_t)idx0[g] * IN_DIM;
  for (int k = f; k < IN_DIM; k += 128) xr[k] = xp[k];
  __syncthreads();
  float a = b0[f];
#pragma unroll 8
  for (int k = 0; k < IN_DIM; ++k) a = fmaf(xr[k], W0[(size_t)k * HID + f], a);
  news[(size_t)g * HID + f] = fmaxf(a, 0.f);
}

// ---------------- z1 = relu([pooled, news] @ W1 + b1) ----------------
__global__ __launch_bounds__(128) void k_hidden(const float* __restrict__ pooled,
                                                const float* __restrict__ news,
                                                const float* __restrict__ W1,
                                                const float* __restrict__ b1,
                                                float* __restrict__ z1) {
  __shared__ float zr[2 * HID];
  int g = blockIdx.x;
  int f = threadIdx.x;
  zr[f] = pooled[(size_t)g * HID + f];
  zr[HID + f] = news[(size_t)g * HID + f];
  __syncthreads();
  float a = b1[f];
#pragma unroll 8
  for (int k = 0; k < 2 * HID; ++k) a = fmaf(zr[k], W1[(size_t)k * HID + f], a);
  z1[(size_t)g * HID + f] = fmaxf(a, 0.f);
}

// ---------------- logits + log_softmax ----------------
__global__ __launch_bounds__(256) void k_out(const float* __restrict__ z1,
                                             const float* __restrict__ W2,
                                             const float* __restrict__ b2,
                                             float* __restrict__ out) {
  int g = blockIdx.x * 256 + threadIdx.x;
  if (g >= NG) return;
  float l0 = b2[0], l1 = b2[1];
#pragma unroll 8
  for (int k = 0; k < HID; ++k) {
    float z = z1[(size_t)g * HID + k];
    l0 = fmaf(z, W2[k * 2 + 0], l0);
    l1 = fmaf(z, W2[k * 2 + 1], l1);
  }
  float m = fmaxf(l0, l1);
  float lse = m + logf(expf(l0 - m) + expf(l1 - m));
  out[g * 2 + 0] = l0 - lse;
  out[g * 2 + 1] = l1 - lse;
}

extern "C" void kernel_launch(void* const* d_in, const int* in_sizes, int n_in,
                              void* d_out, int out_size, void* d_ws, size_t ws_size,
                              hipStream_t stream) {
  const float* x      = (const float*)d_in[0];
  const int* edge     = (const int*)d_in[1];
  const int* batch    = (const int*)d_in[2];
  const float* W_conv = (const float*)d_in[4];
  const float* b_conv = (const float*)d_in[5];
  const float* W0     = (const float*)d_in[6];
  const float* b0     = (const float*)d_in[7];
  const float* W1     = (const float*)d_in[8];
  const float* b1     = (const float*)d_in[9];
  const float* W2     = (const float*)d_in[10];
  const float* b2     = (const float*)d_in[11];
  float* out = (float*)d_out;

  const int* row = edge;
  const int* col = edge + N_EDGES;

  // workspace layout (bytes), all 256B-aligned, total ~110.8 MB
  char* ws = (char*)d_ws;
  float*          h      = (float*)(ws);                         // 102,400,000
  int*            deg    = (int*)  (ws + 102400000);             //     800,000
  float*          dinv   = (float*)(ws + 103200000);             //     800,000
  int*            start  = (int*)  (ws + 104000000);             //     800,004 (N+1)
  int*            cursor = (int*)  (ws + 104800256);             //     800,000
  int*            srcs   = (int*)  (ws + 105600256);             //   3,200,000
  int*            bsum   = (int*)  (ws + 108800256);             //         784
  int*            boff   = (int*)  (ws + 108801280);             //         784
  unsigned short* WT_hi  = (unsigned short*)(ws + 108802304);    //     196,608
  unsigned short* WT_lo  = (unsigned short*)(ws + 108998912);    //     196,608
  unsigned*       pooled = (unsigned*)(ws + 109195520);          //     524,288
  float*          news   = (float*)(ws + 109719808);             //     524,288
  float*          z1     = (float*)(ws + 110244096);             //     524,288
  int*            idx0   = (int*)  (ws + 110768384);             //       4,096

  hipMemsetAsync(deg, 0, (size_t)N_NODES * sizeof(int), stream);
  hipMemsetAsync(pooled, 0, (size_t)NG * HID * sizeof(unsigned), stream);

  k_deg<<<(N_EDGES + 255) / 256, 256, 0, stream>>>(col, deg);
  k_dinv<<<(N_NODES + 255) / 256, 256, 0, stream>>>(deg, dinv);
  k_scan1<<<NSB, 256, 0, stream>>>(deg, bsum);
  k_scan2<<<1, 256, 0, stream>>>(bsum, boff);
  k_scan3<<<NSB, 256, 0, stream>>>(deg, boff, start, cursor);
  k_bin<<<(N_EDGES + 255) / 256, 256, 0, stream>>>(row, col, cursor, srcs);
  k_prepW<<<(IN_DIM * HID + 255) / 256, 256, 0, stream>>>(W_conv, WT_hi, WT_lo);
  k_gemm_mfma<<<(N_NODES + BM - 1) / BM, 256, 0, stream>>>(x, WT_hi, WT_lo, h);
  k_gather<<<((N_NODES + 3) / 4 * 64 + 255) / 256, 256, 0, stream>>>(h, dinv, start, srcs, b_conv, batch, pooled);
  k_idx0<<<(NG + 255) / 256, 256, 0, stream>>>(batch, idx0);
  k_news<<<NG, 128, 0, stream>>>(x, idx0, W0, b0, news);
  k_hidden<<<NG, 128, 0, stream>>>((const float*)pooled, news, W1, b1, z1);
  k_out<<<(NG + 255) / 256, 256, 0, stream>>>(z1, W2, b2, out);
}

// Round 4
// 471.719 us; speedup vs baseline: 2.2483x; 1.0937x over previous
//
#include <hip/hip_runtime.h>

#define N_NODES 200000
#define N_EDGES 800000
#define IN_DIM 768
#define HID 128
#define NG 1024

// MFMA GEMM tile
#define BM 128
#define BK 64
#define LDS_STRIDE (BK + 8)   // 72 fp16 = 144 B row stride: 16B-aligned, ~2-way conflicts only

// scan
#define SCAN_B 1024
#define NSB ((N_NODES + SCAN_B - 1) / SCAN_B)   // 196

typedef _Float16 f16x8 __attribute__((ext_vector_type(8)));
typedef float f32x4 __attribute__((ext_vector_type(4)));

// ---------------- degree ----------------
__global__ __launch_bounds__(256) void k_deg(const int* __restrict__ col, int* __restrict__ deg) {
  int e = blockIdx.x * 256 + threadIdx.x;
  if (e < N_EDGES) atomicAdd(&deg[col[e]], 1);
}

__global__ __launch_bounds__(256) void k_dinv(const int* __restrict__ deg, float* __restrict__ dinv) {
  int i = blockIdx.x * 256 + threadIdx.x;
  if (i < N_NODES) dinv[i] = rsqrtf((float)(deg[i] + 1)); // +1 self loop
}

// ---------------- exclusive scan of deg -> start/cursor ----------------
__global__ __launch_bounds__(256) void k_scan1(const int* __restrict__ deg, int* __restrict__ bsum) {
  __shared__ int red[256];
  int b = blockIdx.x, t = threadIdx.x;
  int base = b * SCAN_B + t * 4;
  int s = 0;
#pragma unroll
  for (int q = 0; q < 4; ++q) { int idx = base + q; if (idx < N_NODES) s += deg[idx]; }
  red[t] = s; __syncthreads();
  for (int o = 128; o > 0; o >>= 1) { if (t < o) red[t] += red[t + o]; __syncthreads(); }
  if (t == 0) bsum[b] = red[0];
}

__global__ __launch_bounds__(256) void k_scan2(const int* __restrict__ bsum, int* __restrict__ boff) {
  __shared__ int s[256];
  int t = threadIdx.x;
  int v = (t < NSB) ? bsum[t] : 0;
  s[t] = v; __syncthreads();
  for (int o = 1; o < 256; o <<= 1) {
    int add = (t >= o) ? s[t - o] : 0;
    __syncthreads();
    s[t] += add;
    __syncthreads();
  }
  if (t < NSB) boff[t] = s[t] - v;  // exclusive
}

__global__ __launch_bounds__(256) void k_scan3(const int* __restrict__ deg, const int* __restrict__ boff,
                                               int* __restrict__ start, int* __restrict__ cursor) {
  __shared__ int s[256];
  int b = blockIdx.x, t = threadIdx.x;
  int base = b * SCAN_B + t * 4;
  int v[4]; int sum = 0;
#pragma unroll
  for (int q = 0; q < 4; ++q) { v[q] = (base + q < N_NODES) ? deg[base + q] : 0; sum += v[q]; }
  s[t] = sum; __syncthreads();
  int my = sum;
  for (int o = 1; o < 256; o <<= 1) {
    int add = (t >= o) ? s[t - o] : 0;
    __syncthreads();
    s[t] += add;
    __syncthreads();
  }
  int excl = s[t] - my + boff[b];
#pragma unroll
  for (int q = 0; q < 4; ++q) {
    int idx = base + q;
    if (idx < N_NODES) { start[idx] = excl; cursor[idx] = excl; excl += v[q]; }
  }
  if (b == 0 && t == 0) start[N_NODES] = N_EDGES;
}

// ---------------- bin edges into CSR ----------------
__global__ __launch_bounds__(256) void k_bin(const int* __restrict__ row, const int* __restrict__ col,
                                             int* __restrict__ cursor, int* __restrict__ srcs) {
  int e = blockIdx.x * 256 + threadIdx.x;
  if (e < N_EDGES) {
    int slot = atomicAdd(&cursor[col[e]], 1);
    srcs[slot] = row[e];
  }
}

// ---------------- W_conv -> transposed fp16 ----------------
__global__ __launch_bounds__(256) void k_prepW(const float* __restrict__ W,
                                               _Float16* __restrict__ WT) {
  int i = blockIdx.x * 256 + threadIdx.x;
  if (i >= IN_DIM * HID) return;
  int k = i / HID, n = i % HID;
  WT[(size_t)n * IN_DIM + k] = (_Float16)W[i];
}

// ---------------- h = x @ W_conv via single-fp16 MFMA ----------------
// x fp32 [N,768]; WT fp16 [128,768] (transposed); h fp32 [N,128]
// error ~|h|*2^-11 ~ 3e-4 << 1.88e-2 threshold (x~N(0,1), |W|<=0.036)
__global__ __launch_bounds__(256, 4) void k_gemm_mfma(const float* __restrict__ x,
                                                      const _Float16* __restrict__ WT,
                                                      float* __restrict__ h) {
  __shared__ _Float16 Asm[BM][LDS_STRIDE];
  __shared__ _Float16 Bsm[HID][LDS_STRIDE];

  const int t = threadIdx.x;
  const int lane = t & 63;
  const int wid = t >> 6;                 // wave 0..3 -> rows wid*32..+31
  const int bm = blockIdx.x * BM;

  f32x4 acc[2][8];
#pragma unroll
  for (int i = 0; i < 2; ++i)
#pragma unroll
    for (int j = 0; j < 8; ++j) acc[i][j] = (f32x4){0.f, 0.f, 0.f, 0.f};

  const int lr = lane & 15;               // A row / B col within 16-tile
  const int lk = (lane >> 4) * 8;         // k offset within 32

  for (int k0 = 0; k0 < IN_DIM; k0 += BK) {
    // ---- stage A: x[bm..bm+128)[k0..k0+64) -> fp16 (RTE), two 16-float chunks ----
    {
      int r = t >> 1;
      int kc = (t & 1) * 32;
      int grow = bm + r;
#pragma unroll
      for (int half = 0; half < 2; ++half) {
        float4 v[4];
        if (grow < N_NODES) {
          const float4* src = (const float4*)(x + (size_t)grow * IN_DIM + k0 + kc + half * 16);
#pragma unroll
          for (int q = 0; q < 4; ++q) v[q] = src[q];
        } else {
          float4 z = {0.f, 0.f, 0.f, 0.f};
#pragma unroll
          for (int q = 0; q < 4; ++q) v[q] = z;
        }
        const float* vf = (const float*)v;
        _Float16 sh[16];
#pragma unroll
        for (int q = 0; q < 16; ++q) sh[q] = (_Float16)vf[q];
#pragma unroll
        for (int q = 0; q < 2; ++q)
          *(f16x8*)&Asm[r][kc + half * 16 + q * 8] = *(const f16x8*)&sh[q * 8];
      }
    }
    // ---- stage B: WT[0..128)[k0..k0+64) ----
    {
      int n = t >> 1;
      int kc = (t & 1) * 32;
      const f16x8* src = (const f16x8*)(WT + (size_t)n * IN_DIM + k0 + kc);
#pragma unroll
      for (int q = 0; q < 4; ++q)
        *(f16x8*)&Bsm[n][kc + q * 8] = src[q];
    }
    __syncthreads();

#pragma unroll
    for (int ks = 0; ks < 2; ++ks) {
      const int kb = ks * 32 + lk;
      f16x8 a[2];
#pragma unroll
      for (int rt = 0; rt < 2; ++rt)
        a[rt] = *(const f16x8*)&Asm[wid * 32 + rt * 16 + lr][kb];
#pragma unroll
      for (int ct = 0; ct < 8; ++ct) {
        f16x8 b = *(const f16x8*)&Bsm[ct * 16 + lr][kb];
#pragma unroll
        for (int rt = 0; rt < 2; ++rt)
          acc[rt][ct] = __builtin_amdgcn_mfma_f32_16x16x32_f16(a[rt], b, acc[rt][ct], 0, 0, 0);
      }
    }
    __syncthreads();
  }

  // epilogue: D row = (lane>>4)*4 + j, col = lane&15
  const int dcol = lane & 15;
  const int drow = (lane >> 4) * 4;
#pragma unroll
  for (int rt = 0; rt < 2; ++rt) {
#pragma unroll
    for (int j = 0; j < 4; ++j) {
      int grow = bm + wid * 32 + rt * 16 + drow + j;
      if (grow < N_NODES) {
        float* dst = h + (size_t)grow * HID;
#pragma unroll
        for (int ct = 0; ct < 8; ++ct) dst[ct * 16 + dcol] = acc[rt][ct][j];
      }
    }
  }
}

// ---------------- fused gather + self-loop + bias + relu + max-pool ----------------
__global__ __launch_bounds__(256) void k_gather(const float* __restrict__ h,
                                                const float* __restrict__ dinv,
                                                const int* __restrict__ start,
                                                const int* __restrict__ srcs,
                                                const float* __restrict__ b_conv,
                                                const int* __restrict__ batch,
                                                unsigned* __restrict__ pooled) {
  int gid = blockIdx.x * 256 + threadIdx.x;
  int wv = gid >> 6, lane = gid & 63;
  int n0 = wv * 4;
  if (n0 >= N_NODES) return;
  float bc0 = b_conv[lane], bc1 = b_conv[lane + 64];
  int gcur = -1;
  float m0 = 0.f, m1 = 0.f;
  int nend = n0 + 4 < N_NODES ? n0 + 4 : N_NODES;
  for (int i = n0; i < nend; ++i) {
    float di = dinv[i];
    const float* hi_ = h + (size_t)i * HID;
    float sw = di * di;
    float a0 = hi_[lane] * sw;
    float a1 = hi_[lane + 64] * sw;
    int s = start[i], e = start[i + 1];
    for (int sl = s; sl < e; ++sl) {
      int src = srcs[sl];                 // wave-broadcast
      float w = dinv[src] * di;           // wave-broadcast
      const float* hs = h + (size_t)src * HID;
      a0 = fmaf(hs[lane], w, a0);
      a1 = fmaf(hs[lane + 64], w, a1);
    }
    a0 = fmaxf(a0 + bc0, 0.f);
    a1 = fmaxf(a1 + bc1, 0.f);
    int g = batch[i];
    if (g != gcur) {
      if (gcur >= 0) {
        atomicMax(&pooled[(size_t)gcur * HID + lane], __float_as_uint(m0));
        atomicMax(&pooled[(size_t)gcur * HID + lane + 64], __float_as_uint(m1));
      }
      gcur = g; m0 = a0; m1 = a1;
    } else {
      m0 = fmaxf(m0, a0);
      m1 = fmaxf(m1, a1);
    }
  }
  if (gcur >= 0) {
    atomicMax(&pooled[(size_t)gcur * HID + lane], __float_as_uint(m0));
    atomicMax(&pooled[(size_t)gcur * HID + lane + 64], __float_as_uint(m1));
  }
}

// ---------------- idx0 = searchsorted(batch, arange(NG)) ----------------
__global__ __launch_bounds__(256) void k_idx0(const int* __restrict__ batch, int* __restrict__ idx0) {
  int g = blockIdx.x * 256 + threadIdx.x;
  if (g >= NG) return;
  int lo = 0, hi = N_NODES;
  while (lo < hi) {
    int mid = (lo + hi) >> 1;
    if (batch[mid] < g) lo = mid + 1; else hi = mid;
  }
  idx0[g] = lo < N_NODES ? lo : N_NODES - 1;
}

// ---------------- news = relu(x[idx0] @ W0 + b0) ----------------
__global__ __launch_bounds__(128) void k_news(const float* __restrict__ x,
                                              const int* __restrict__ idx0,
                                              const float* __restrict__ W0,
                                              const float* __restrict__ b0,
                                              float* __restrict__ news) {
  __shared__ float xr[IN_DIM];
  int g = blockIdx.x;
  int f = threadIdx.x;
  const float* xp = x + (size_t)idx0[g] * IN_DIM;
  for (int k = f; k < IN_DIM; k += 128) xr[k] = xp[k];
  __syncthreads();
  float a = b0[f];
#pragma unroll 8
  for (int k = 0; k < IN_DIM; ++k) a = fmaf(xr[k], W0[(size_t)k * HID + f], a);
  news[(size_t)g * HID + f] = fmaxf(a, 0.f);
}

// ---------------- z1 = relu([pooled, news] @ W1 + b1) ----------------
__global__ __launch_bounds__(128) void k_hidden(const float* __restrict__ pooled,
                                                const float* __restrict__ news,
                                                const float* __restrict__ W1,
                                                const float* __restrict__ b1,
                                                float* __restrict__ z1) {
  __shared__ float zr[2 * HID];
  int g = blockIdx.x;
  int f = threadIdx.x;
  zr[f] = pooled[(size_t)g * HID + f];
  zr[HID + f] = news[(size_t)g * HID + f];
  __syncthreads();
  float a = b1[f];
#pragma unroll 8
  for (int k = 0; k < 2 * HID; ++k) a = fmaf(zr[k], W1[(size_t)k * HID + f], a);
  z1[(size_t)g * HID + f] = fmaxf(a, 0.f);
}

// ---------------- logits + log_softmax ----------------
__global__ __launch_bounds__(256) void k_out(const float* __restrict__ z1,
                                             const float* __restrict__ W2,
                                             const float* __restrict__ b2,
                                             float* __restrict__ out) {
  int g = blockIdx.x * 256 + threadIdx.x;
  if (g >= NG) return;
  float l0 = b2[0], l1 = b2[1];
#pragma unroll 8
  for (int k = 0; k < HID; ++k) {
    float z = z1[(size_t)g * HID + k];
    l0 = fmaf(z, W2[k * 2 + 0], l0);
    l1 = fmaf(z, W2[k * 2 + 1], l1);
  }
  float m = fmaxf(l0, l1);
  float lse = m + logf(expf(l0 - m) + expf(l1 - m));
  out[g * 2 + 0] = l0 - lse;
  out[g * 2 + 1] = l1 - lse;
}

extern "C" void kernel_launch(void* const* d_in, const int* in_sizes, int n_in,
                              void* d_out, int out_size, void* d_ws, size_t ws_size,
                              hipStream_t stream) {
  const float* x      = (const float*)d_in[0];
  const int* edge     = (const int*)d_in[1];
  const int* batch    = (const int*)d_in[2];
  const float* W_conv = (const float*)d_in[4];
  const float* b_conv = (const float*)d_in[5];
  const float* W0     = (const float*)d_in[6];
  const float* b0     = (const float*)d_in[7];
  const float* W1     = (const float*)d_in[8];
  const float* b1     = (const float*)d_in[9];
  const float* W2     = (const float*)d_in[10];
  const float* b2     = (const float*)d_in[11];
  float* out = (float*)d_out;

  const int* row = edge;
  const int* col = edge + N_EDGES;

  // workspace layout (bytes), 256B-aligned, total ~110.6 MB
  char* ws = (char*)d_ws;
  float*     h      = (float*)(ws);                      // 102,400,000
  int*       deg    = (int*)  (ws + 102400000);          //     800,000
  float*     dinv   = (float*)(ws + 103200000);          //     800,000
  int*       start  = (int*)  (ws + 104000000);          //     800,004 (N+1)
  int*       cursor = (int*)  (ws + 104800256);          //     800,000
  int*       srcs   = (int*)  (ws + 105600256);          //   3,200,000
  int*       bsum   = (int*)  (ws + 108800256);          //         784
  int*       boff   = (int*)  (ws + 108801280);          //         784
  _Float16*  WT     = (_Float16*)(ws + 108802304);       //     196,608
  unsigned*  pooled = (unsigned*)(ws + 108998912);       //     524,288
  float*     news   = (float*)(ws + 109523200);          //     524,288
  float*     z1     = (float*)(ws + 110047488);          //     524,288
  int*       idx0   = (int*)  (ws + 110571776);          //       4,096

  hipMemsetAsync(deg, 0, (size_t)N_NODES * sizeof(int), stream);
  hipMemsetAsync(pooled, 0, (size_t)NG * HID * sizeof(unsigned), stream);

  k_deg<<<(N_EDGES + 255) / 256, 256, 0, stream>>>(col, deg);
  k_dinv<<<(N_NODES + 255) / 256, 256, 0, stream>>>(deg, dinv);
  k_scan1<<<NSB, 256, 0, stream>>>(deg, bsum);
  k_scan2<<<1, 256, 0, stream>>>(bsum, boff);
  k_scan3<<<NSB, 256, 0, stream>>>(deg, boff, start, cursor);
  k_bin<<<(N_EDGES + 255) / 256, 256, 0, stream>>>(row, col, cursor, srcs);
  k_prepW<<<(IN_DIM * HID + 255) / 256, 256, 0, stream>>>(W_conv, WT);
  k_gemm_mfma<<<(N_NODES + BM - 1) / BM, 256, 0, stream>>>(x, WT, h);
  k_gather<<<((N_NODES + 3) / 4 * 64 + 255) / 256, 256, 0, stream>>>(h, dinv, start, srcs, b_conv, batch, pooled);
  k_idx0<<<(NG + 255) / 256, 256, 0, stream>>>(batch, idx0);
  k_news<<<NG, 128, 0, stream>>>(x, idx0, W0, b0, news);
  k_hidden<<<NG, 128, 0, stream>>>((const float*)pooled, news, W1, b1, z1);
  k_out<<<(NG + 255) / 256, 256, 0, stream>>>(z1, W2, b2, out);
}

// Round 5
// 417.477 us; speedup vs baseline: 2.5404x; 1.1299x over previous
//
#include <hip/hip_runtime.h>

#define N_NODES 200000
#define N_EDGES 800000
#define IN_DIM 768
#define HID 128
#define NG 1024

// MFMA GEMM tile
#define BM 128
#define BKT 64
#define BSTRIDE (BKT + 8)   // 72 fp16 = 144 B row stride: 16B-aligned, 2-way conflicts (free)

// scan
#define SCAN_B 1024
#define NSB ((N_NODES + SCAN_B - 1) / SCAN_B)   // 196

typedef _Float16 f16x8 __attribute__((ext_vector_type(8)));
typedef float f32x4 __attribute__((ext_vector_type(4)));

// ---------------- degree ----------------
__global__ __launch_bounds__(256) void k_deg(const int* __restrict__ col, int* __restrict__ deg) {
  int e = blockIdx.x * 256 + threadIdx.x;
  if (e < N_EDGES) atomicAdd(&deg[col[e]], 1);
}

__global__ __launch_bounds__(256) void k_dinv(const int* __restrict__ deg, float* __restrict__ dinv) {
  int i = blockIdx.x * 256 + threadIdx.x;
  if (i < N_NODES) dinv[i] = rsqrtf((float)(deg[i] + 1)); // +1 self loop
}

// ---------------- exclusive scan of deg -> start/cursor ----------------
__global__ __launch_bounds__(256) void k_scan1(const int* __restrict__ deg, int* __restrict__ bsum) {
  __shared__ int red[256];
  int b = blockIdx.x, t = threadIdx.x;
  int base = b * SCAN_B + t * 4;
  int s = 0;
#pragma unroll
  for (int q = 0; q < 4; ++q) { int idx = base + q; if (idx < N_NODES) s += deg[idx]; }
  red[t] = s; __syncthreads();
  for (int o = 128; o > 0; o >>= 1) { if (t < o) red[t] += red[t + o]; __syncthreads(); }
  if (t == 0) bsum[b] = red[0];
}

__global__ __launch_bounds__(256) void k_scan2(const int* __restrict__ bsum, int* __restrict__ boff) {
  __shared__ int s[256];
  int t = threadIdx.x;
  int v = (t < NSB) ? bsum[t] : 0;
  s[t] = v; __syncthreads();
  for (int o = 1; o < 256; o <<= 1) {
    int add = (t >= o) ? s[t - o] : 0;
    __syncthreads();
    s[t] += add;
    __syncthreads();
  }
  if (t < NSB) boff[t] = s[t] - v;  // exclusive
}

__global__ __launch_bounds__(256) void k_scan3(const int* __restrict__ deg, const int* __restrict__ boff,
                                               int* __restrict__ start, int* __restrict__ cursor) {
  __shared__ int s[256];
  int b = blockIdx.x, t = threadIdx.x;
  int base = b * SCAN_B + t * 4;
  int v[4]; int sum = 0;
#pragma unroll
  for (int q = 0; q < 4; ++q) { v[q] = (base + q < N_NODES) ? deg[base + q] : 0; sum += v[q]; }
  s[t] = sum; __syncthreads();
  int my = sum;
  for (int o = 1; o < 256; o <<= 1) {
    int add = (t >= o) ? s[t - o] : 0;
    __syncthreads();
    s[t] += add;
    __syncthreads();
  }
  int excl = s[t] - my + boff[b];
#pragma unroll
  for (int q = 0; q < 4; ++q) {
    int idx = base + q;
    if (idx < N_NODES) { start[idx] = excl; cursor[idx] = excl; excl += v[q]; }
  }
  if (b == 0 && t == 0) start[N_NODES] = N_EDGES;
}

// ---------------- bin edges into CSR with precomputed weights ----------------
__global__ __launch_bounds__(256) void k_bin(const int* __restrict__ row, const int* __restrict__ col,
                                             const float* __restrict__ dinv,
                                             int* __restrict__ cursor, int2* __restrict__ ew) {
  int e = blockIdx.x * 256 + threadIdx.x;
  if (e < N_EDGES) {
    int r = row[e], c = col[e];
    int slot = atomicAdd(&cursor[c], 1);
    float w = dinv[r] * dinv[c];
    ew[slot] = make_int2(r, __float_as_int(w));
  }
}

// ---------------- W_conv -> transposed fp16 ----------------
__global__ __launch_bounds__(256) void k_prepW(const float* __restrict__ W,
                                               _Float16* __restrict__ WT) {
  int i = blockIdx.x * 256 + threadIdx.x;
  if (i >= IN_DIM * HID) return;
  int k = i / HID, n = i % HID;
  WT[(size_t)n * IN_DIM + k] = (_Float16)W[i];
}

// ---------------- h = x @ W_conv : fp16 MFMA, A direct-from-global, B in LDS ----------------
__global__ __launch_bounds__(256, 4) void k_gemm_mfma(const float* __restrict__ x,
                                                      const _Float16* __restrict__ WT,
                                                      float* __restrict__ h) {
  __shared__ _Float16 Bsm[HID][BSTRIDE];

  const int t = threadIdx.x;
  const int lane = t & 63;
  const int wid = t >> 6;                 // wave 0..3 -> rows wid*32..+31
  const int bm = blockIdx.x * BM;

  f32x4 acc[2][8];
#pragma unroll
  for (int i = 0; i < 2; ++i)
#pragma unroll
    for (int j = 0; j < 8; ++j) acc[i][j] = (f32x4){0.f, 0.f, 0.f, 0.f};

  const int lr = lane & 15;               // A row / B col within 16-tile
  const int lk = (lane >> 4) * 8;         // k offset within 32

  // B staging coords: thread stages col bcol, k-half bkh (64B contiguous)
  const int bcol = t >> 1;
  const int bkh = (t & 1) * 32;

  // A row pointers (clamped; OOB rows compute garbage, discarded at store)
  const float* xrow[2];
#pragma unroll
  for (int rt = 0; rt < 2; ++rt) {
    int r = bm + wid * 32 + rt * 16 + lr;
    if (r >= N_NODES) r = N_NODES - 1;
    xrow[rt] = x + (size_t)r * IN_DIM;
  }

  for (int k0 = 0; k0 < IN_DIM; k0 += BKT) {
    // prefetch B tile (raw fp16) into regs
    f16x8 breg[4];
    {
      const f16x8* src = (const f16x8*)(WT + (size_t)bcol * IN_DIM + k0 + bkh);
#pragma unroll
      for (int q = 0; q < 4; ++q) breg[q] = src[q];
    }
    // prefetch A fragments (fp32) into regs: 2 rt x 2 ks x 8 floats
    float4 areg[2][2][2];
#pragma unroll
    for (int rt = 0; rt < 2; ++rt)
#pragma unroll
      for (int ks = 0; ks < 2; ++ks) {
        const float4* src = (const float4*)(xrow[rt] + k0 + ks * 32 + lk);
        areg[rt][ks][0] = src[0];
        areg[rt][ks][1] = src[1];
      }
    __syncthreads();                       // previous tile's B reads complete
#pragma unroll
    for (int q = 0; q < 4; ++q)
      *(f16x8*)&Bsm[bcol][bkh + q * 8] = breg[q];
    __syncthreads();

    // convert A to fp16 fragments
    f16x8 af[2][2];
#pragma unroll
    for (int rt = 0; rt < 2; ++rt)
#pragma unroll
      for (int ks = 0; ks < 2; ++ks) {
        const float* vf = (const float*)areg[rt][ks];
#pragma unroll
        for (int q = 0; q < 8; ++q) af[rt][ks][q] = (_Float16)vf[q];
      }

#pragma unroll
    for (int ks = 0; ks < 2; ++ks)
#pragma unroll
      for (int ct = 0; ct < 8; ++ct) {
        f16x8 bf = *(const f16x8*)&Bsm[ct * 16 + lr][ks * 32 + lk];
        acc[0][ct] = __builtin_amdgcn_mfma_f32_16x16x32_f16(af[0][ks], bf, acc[0][ct], 0, 0, 0);
        acc[1][ct] = __builtin_amdgcn_mfma_f32_16x16x32_f16(af[1][ks], bf, acc[1][ct], 0, 0, 0);
      }
  }

  // epilogue: D row = (lane>>4)*4 + j, col = lane&15
  const int dcol = lane & 15;
  const int drow = (lane >> 4) * 4;
#pragma unroll
  for (int rt = 0; rt < 2; ++rt) {
#pragma unroll
    for (int j = 0; j < 4; ++j) {
      int grow = bm + wid * 32 + rt * 16 + drow + j;
      if (grow < N_NODES) {
        float* dst = h + (size_t)grow * HID;
#pragma unroll
        for (int ct = 0; ct < 8; ++ct) dst[ct * 16 + dcol] = acc[rt][ct][j];
      }
    }
  }
}

// ---------------- fused gather + self-loop + bias + relu + max-pool ----------------
// wave per 4 consecutive nodes; lane owns features (lane, lane+64).
// Edge records preloaded cooperatively, broadcast via shfl; 2 independent fma chains.
__global__ __launch_bounds__(256) void k_gather(const float* __restrict__ h,
                                                const float* __restrict__ dinv,
                                                const int* __restrict__ start,
                                                const int2* __restrict__ ew,
                                                const float* __restrict__ b_conv,
                                                const int* __restrict__ batch,
                                                unsigned* __restrict__ pooled) {
  int gid = blockIdx.x * 256 + threadIdx.x;
  int wv = gid >> 6, lane = gid & 63;
  int n0 = wv * 4;
  if (n0 >= N_NODES) return;
  float bc0 = b_conv[lane], bc1 = b_conv[lane + 64];
  int gcur = -1;
  float m0 = 0.f, m1 = 0.f;
  int nend = n0 + 4 < N_NODES ? n0 + 4 : N_NODES;
  for (int i = n0; i < nend; ++i) {
    float di = dinv[i];
    float sw = di * di;
    const float* hi_ = h + (size_t)i * HID;
    float a0 = hi_[lane] * sw;
    float a1 = hi_[lane + 64] * sw;
    float p0 = 0.f, p1 = 0.f;
    int s = start[i], e = start[i + 1];
    for (int c = s; c < e; c += 64) {
      int cnt = e - c; if (cnt > 64) cnt = 64;
      int2 my = (lane < cnt) ? ew[c + lane] : make_int2(0, 0);
      int j = 0;
      for (; j + 1 < cnt; j += 2) {
        int s0 = __shfl(my.x, j), s1 = __shfl(my.x, j + 1);
        float w0 = __uint_as_float((unsigned)__shfl(my.y, j));
        float w1 = __uint_as_float((unsigned)__shfl(my.y, j + 1));
        const float* h0 = h + (size_t)s0 * HID;
        const float* h1 = h + (size_t)s1 * HID;
        a0 = fmaf(h0[lane], w0, a0);
        p0 = fmaf(h1[lane], w1, p0);
        a1 = fmaf(h0[lane + 64], w0, a1);
        p1 = fmaf(h1[lane + 64], w1, p1);
      }
      if (j < cnt) {
        int s0 = __shfl(my.x, j);
        float w0 = __uint_as_float((unsigned)__shfl(my.y, j));
        const float* h0 = h + (size_t)s0 * HID;
        a0 = fmaf(h0[lane], w0, a0);
        a1 = fmaf(h0[lane + 64], w0, a1);
      }
    }
    a0 += p0; a1 += p1;
    a0 = fmaxf(a0 + bc0, 0.f);
    a1 = fmaxf(a1 + bc1, 0.f);
    int g = batch[i];
    if (g != gcur) {
      if (gcur >= 0) {
        atomicMax(&pooled[(size_t)gcur * HID + lane], __float_as_uint(m0));
        atomicMax(&pooled[(size_t)gcur * HID + lane + 64], __float_as_uint(m1));
      }
      gcur = g; m0 = a0; m1 = a1;
    } else {
      m0 = fmaxf(m0, a0);
      m1 = fmaxf(m1, a1);
    }
  }
  if (gcur >= 0) {
    atomicMax(&pooled[(size_t)gcur * HID + lane], __float_as_uint(m0));
    atomicMax(&pooled[(size_t)gcur * HID + lane + 64], __float_as_uint(m1));
  }
}

// ---------------- idx0 = searchsorted(batch, arange(NG)) ----------------
__global__ __launch_bounds__(256) void k_idx0(const int* __restrict__ batch, int* __restrict__ idx0) {
  int g = blockIdx.x * 256 + threadIdx.x;
  if (g >= NG) return;
  int lo = 0, hi = N_NODES;
  while (lo < hi) {
    int mid = (lo + hi) >> 1;
    if (batch[mid] < g) lo = mid + 1; else hi = mid;
  }
  idx0[g] = lo < N_NODES ? lo : N_NODES - 1;
}

// ---------------- news = relu(x[idx0] @ W0 + b0) ----------------
__global__ __launch_bounds__(128) void k_news(const float* __restrict__ x,
                                              const int* __restrict__ idx0,
                                              const float* __restrict__ W0,
                                              const float* __restrict__ b0,
                                              float* __restrict__ news) {
  __shared__ float xr[IN_DIM];
  int g = blockIdx.x;
  int f = threadIdx.x;
  const float* xp = x + (size_t)idx0[g] * IN_DIM;
  for (int k = f; k < IN_DIM; k += 128) xr[k] = xp[k];
  __syncthreads();
  float a = b0[f];
#pragma unroll 8
  for (int k = 0; k < IN_DIM; ++k) a = fmaf(xr[k], W0[(size_t)k * HID + f], a);
  news[(size_t)g * HID + f] = fmaxf(a, 0.f);
}

// ---------------- z1 = relu([pooled, news] @ W1 + b1) ----------------
__global__ __launch_bounds__(128) void k_hidden(const float* __restrict__ pooled,
                                                const float* __restrict__ news,
                                                const float* __restrict__ W1,
                                                const float* __restrict__ b1,
                                                float* __restrict__ z1) {
  __shared__ float zr[2 * HID];
  int g = blockIdx.x;
  int f = threadIdx.x;
  zr[f] = pooled[(size_t)g * HID + f];
  zr[HID + f] = news[(size_t)g * HID + f];
  __syncthreads();
  float a = b1[f];
#pragma unroll 8
  for (int k = 0; k < 2 * HID; ++k) a = fmaf(zr[k], W1[(size_t)k * HID + f], a);
  z1[(size_t)g * HID + f] = fmaxf(a, 0.f);
}

// ---------------- logits + log_softmax ----------------
__global__ __launch_bounds__(256) void k_out(const float* __restrict__ z1,
                                             const float* __restrict__ W2,
                                             const float* __restrict__ b2,
                                             float* __restrict__ out) {
  int g = blockIdx.x * 256 + threadIdx.x;
  if (g >= NG) return;
  float l0 = b2[0], l1 = b2[1];
#pragma unroll 8
  for (int k = 0; k < HID; ++k) {
    float z = z1[(size_t)g * HID + k];
    l0 = fmaf(z, W2[k * 2 + 0], l0);
    l1 = fmaf(z, W2[k * 2 + 1], l1);
  }
  float m = fmaxf(l0, l1);
  float lse = m + logf(expf(l0 - m) + expf(l1 - m));
  out[g * 2 + 0] = l0 - lse;
  out[g * 2 + 1] = l1 - lse;
}

extern "C" void kernel_launch(void* const* d_in, const int* in_sizes, int n_in,
                              void* d_out, int out_size, void* d_ws, size_t ws_size,
                              hipStream_t stream) {
  const float* x      = (const float*)d_in[0];
  const int* edge     = (const int*)d_in[1];
  const int* batch    = (const int*)d_in[2];
  const float* W_conv = (const float*)d_in[4];
  const float* b_conv = (const float*)d_in[5];
  const float* W0     = (const float*)d_in[6];
  const float* b0     = (const float*)d_in[7];
  const float* W1     = (const float*)d_in[8];
  const float* b1     = (const float*)d_in[9];
  const float* W2     = (const float*)d_in[10];
  const float* b2     = (const float*)d_in[11];
  float* out = (float*)d_out;

  const int* row = edge;
  const int* col = edge + N_EDGES;

  // workspace layout (bytes), 256B-aligned, total ~113.8 MB
  char* ws = (char*)d_ws;
  float*     h      = (float*)(ws);                      // 102,400,000
  int*       deg    = (int*)  (ws + 102400000);          //     800,000
  float*     dinv   = (float*)(ws + 103200000);          //     800,000
  int*       start  = (int*)  (ws + 104000000);          //     800,004 (N+1)
  int*       cursor = (int*)  (ws + 104800256);          //     800,000
  int2*      ew     = (int2*) (ws + 105600256);          //   6,400,000
  int*       bsum   = (int*)  (ws + 112000256);          //         784
  int*       boff   = (int*)  (ws + 112001280);          //         784
  _Float16*  WT     = (_Float16*)(ws + 112002304);       //     196,608
  unsigned*  pooled = (unsigned*)(ws + 112198912);       //     524,288
  float*     news   = (float*)(ws + 112723200);          //     524,288
  float*     z1     = (float*)(ws + 113247488);          //     524,288
  int*       idx0   = (int*)  (ws + 113771776);          //       4,096

  hipMemsetAsync(deg, 0, (size_t)N_NODES * sizeof(int), stream);
  hipMemsetAsync(pooled, 0, (size_t)NG * HID * sizeof(unsigned), stream);

  k_deg<<<(N_EDGES + 255) / 256, 256, 0, stream>>>(col, deg);
  k_dinv<<<(N_NODES + 255) / 256, 256, 0, stream>>>(deg, dinv);
  k_scan1<<<NSB, 256, 0, stream>>>(deg, bsum);
  k_scan2<<<1, 256, 0, stream>>>(bsum, boff);
  k_scan3<<<NSB, 256, 0, stream>>>(deg, boff, start, cursor);
  k_bin<<<(N_EDGES + 255) / 256, 256, 0, stream>>>(row, col, dinv, cursor, ew);
  k_prepW<<<(IN_DIM * HID + 255) / 256, 256, 0, stream>>>(W_conv, WT);
  k_gemm_mfma<<<(N_NODES + BM - 1) / BM, 256, 0, stream>>>(x, WT, h);
  k_gather<<<((N_NODES + 3) / 4 * 64 + 255) / 256, 256, 0, stream>>>(h, dinv, start, ew, b_conv, batch, pooled);
  k_idx0<<<(NG + 255) / 256, 256, 0, stream>>>(batch, idx0);
  k_news<<<NG, 128, 0, stream>>>(x, idx0, W0, b0, news);
  k_hidden<<<NG, 128, 0, stream>>>((const float*)pooled, news, W1, b1, z1);
  k_out<<<(NG + 255) / 256, 256, 0, stream>>>(z1, W2, b2, out);
}

// Round 6
// 415.396 us; speedup vs baseline: 2.5531x; 1.0050x over previous
//
#include <hip/hip_runtime.h>

#define N_NODES 200000
#define N_EDGES 800000
#define IN_DIM 768
#define HID 128
#define NG 1024

// MFMA GEMM tile
#define BM 128
#define BKT 64
#define NT (IN_DIM / BKT)     // 12
#define BSTRIDE (BKT + 8)     // 72 fp16 = 144 B row stride: 16B-aligned, 2-way conflicts (free)

// scan
#define SCAN_B 1024
#define NSB ((N_NODES + SCAN_B - 1) / SCAN_B)   // 196

typedef _Float16 f16x8 __attribute__((ext_vector_type(8)));
typedef float f32x4 __attribute__((ext_vector_type(4)));

__device__ inline void unpack16(unsigned u, float& a, float& b) {
  union { unsigned v; _Float16 f[2]; } c; c.v = u;
  a = (float)c.f[0]; b = (float)c.f[1];
}

// ---------------- degree ----------------
__global__ __launch_bounds__(256) void k_deg(const int* __restrict__ col, int* __restrict__ deg) {
  int e = blockIdx.x * 256 + threadIdx.x;
  if (e < N_EDGES) atomicAdd(&deg[col[e]], 1);
}

// ---------------- exclusive scan of deg -> start/cursor (+dinv fused) ----------------
__global__ __launch_bounds__(256) void k_scan1(const int* __restrict__ deg, int* __restrict__ bsum) {
  __shared__ int red[256];
  int b = blockIdx.x, t = threadIdx.x;
  int base = b * SCAN_B + t * 4;
  int s = 0;
#pragma unroll
  for (int q = 0; q < 4; ++q) { int idx = base + q; if (idx < N_NODES) s += deg[idx]; }
  red[t] = s; __syncthreads();
  for (int o = 128; o > 0; o >>= 1) { if (t < o) red[t] += red[t + o]; __syncthreads(); }
  if (t == 0) bsum[b] = red[0];
}

__global__ __launch_bounds__(256) void k_scan2(const int* __restrict__ bsum, int* __restrict__ boff) {
  __shared__ int s[256];
  int t = threadIdx.x;
  int v = (t < NSB) ? bsum[t] : 0;
  s[t] = v; __syncthreads();
  for (int o = 1; o < 256; o <<= 1) {
    int add = (t >= o) ? s[t - o] : 0;
    __syncthreads();
    s[t] += add;
    __syncthreads();
  }
  if (t < NSB) boff[t] = s[t] - v;  // exclusive
}

__global__ __launch_bounds__(256) void k_scan3(const int* __restrict__ deg, const int* __restrict__ boff,
                                               int* __restrict__ start, int* __restrict__ cursor,
                                               float* __restrict__ dinv) {
  __shared__ int s[256];
  int b = blockIdx.x, t = threadIdx.x;
  int base = b * SCAN_B + t * 4;
  int v[4]; int sum = 0;
#pragma unroll
  for (int q = 0; q < 4; ++q) { v[q] = (base + q < N_NODES) ? deg[base + q] : 0; sum += v[q]; }
  s[t] = sum; __syncthreads();
  int my = sum;
  for (int o = 1; o < 256; o <<= 1) {
    int add = (t >= o) ? s[t - o] : 0;
    __syncthreads();
    s[t] += add;
    __syncthreads();
  }
  int excl = s[t] - my + boff[b];
#pragma unroll
  for (int q = 0; q < 4; ++q) {
    int idx = base + q;
    if (idx < N_NODES) {
      start[idx] = excl; cursor[idx] = excl; excl += v[q];
      dinv[idx] = rsqrtf((float)(v[q] + 1));   // +1 self loop
    }
  }
  if (b == 0 && t == 0) start[N_NODES] = N_EDGES;
}

// ---------------- bin edges into CSR with precomputed weights ----------------
__global__ __launch_bounds__(256) void k_bin(const int* __restrict__ row, const int* __restrict__ col,
                                             const float* __restrict__ dinv,
                                             int* __restrict__ cursor, int2* __restrict__ ew) {
  int e = blockIdx.x * 256 + threadIdx.x;
  if (e < N_EDGES) {
    int r = row[e], c = col[e];
    int slot = atomicAdd(&cursor[c], 1);
    float w = dinv[r] * dinv[c];
    ew[slot] = make_int2(r, __float_as_int(w));
  }
}

// ---------------- W_conv -> transposed fp16 ----------------
__global__ __launch_bounds__(256) void k_prepW(const float* __restrict__ W,
                                               _Float16* __restrict__ WT) {
  int i = blockIdx.x * 256 + threadIdx.x;
  if (i >= IN_DIM * HID) return;
  int k = i / HID, n = i % HID;
  WT[(size_t)n * IN_DIM + k] = (_Float16)W[i];
}

// ---------------- h16 = fp16(x @ W_conv) : fp16 MFMA, double-buffered ----------------
__global__ __launch_bounds__(256, 3) void k_gemm_mfma(const float* __restrict__ x,
                                                      const _Float16* __restrict__ WT,
                                                      _Float16* __restrict__ h16) {
  __shared__ _Float16 Bsm[2][HID][BSTRIDE];   // 36.9 KB

  const int t = threadIdx.x;
  const int lane = t & 63;
  const int wid = t >> 6;                 // wave 0..3 -> rows wid*32..+31
  const int bm = blockIdx.x * BM;

  f32x4 acc[2][8];
#pragma unroll
  for (int i = 0; i < 2; ++i)
#pragma unroll
    for (int j = 0; j < 8; ++j) acc[i][j] = (f32x4){0.f, 0.f, 0.f, 0.f};

  const int lr = lane & 15;               // A row / B col within 16-tile
  const int lk = (lane >> 4) * 8;         // k offset within 32
  const int bcol = t >> 1;                // B staging: column
  const int bkh = (t & 1) * 32;           // B staging: k-half (64 B contiguous)

  const float* xrow[2];
#pragma unroll
  for (int rt = 0; rt < 2; ++rt) {
    int r = bm + wid * 32 + rt * 16 + lr;
    if (r >= N_NODES) r = N_NODES - 1;    // clamp; garbage discarded at store
    xrow[rt] = x + (size_t)r * IN_DIM;
  }

  f16x8 breg[4];
  float4 areg[2][2][2];
  f16x8 af[2][2];

  // ---- prologue: tile 0 ----
  {
    const f16x8* src = (const f16x8*)(WT + (size_t)bcol * IN_DIM + bkh);
#pragma unroll
    for (int q = 0; q < 4; ++q) breg[q] = src[q];
#pragma unroll
    for (int rt = 0; rt < 2; ++rt)
#pragma unroll
      for (int ks = 0; ks < 2; ++ks) {
        const float4* s = (const float4*)(xrow[rt] + ks * 32 + lk);
        areg[rt][ks][0] = s[0]; areg[rt][ks][1] = s[1];
      }
#pragma unroll
    for (int rt = 0; rt < 2; ++rt)
#pragma unroll
      for (int ks = 0; ks < 2; ++ks) {
        const float* vf = (const float*)areg[rt][ks];
#pragma unroll
        for (int q = 0; q < 8; ++q) af[rt][ks][q] = (_Float16)vf[q];
      }
#pragma unroll
    for (int q = 0; q < 4; ++q)
      *(f16x8*)&Bsm[0][bcol][bkh + q * 8] = breg[q];
  }
  __syncthreads();

  // ---- main loop: compute tile tt while loading tile tt+1 ----
  for (int tt = 0; tt < NT; ++tt) {
    const int cur = tt & 1;
    const bool more = tt + 1 < NT;
    if (more) {
      const int k1 = (tt + 1) * BKT;
      const f16x8* src = (const f16x8*)(WT + (size_t)bcol * IN_DIM + k1 + bkh);
#pragma unroll
      for (int q = 0; q < 4; ++q) breg[q] = src[q];
#pragma unroll
      for (int rt = 0; rt < 2; ++rt)
#pragma unroll
        for (int ks = 0; ks < 2; ++ks) {
          const float4* s = (const float4*)(xrow[rt] + k1 + ks * 32 + lk);
          areg[rt][ks][0] = s[0]; areg[rt][ks][1] = s[1];
        }
    }
#pragma unroll
    for (int ks = 0; ks < 2; ++ks)
#pragma unroll
      for (int ct = 0; ct < 8; ++ct) {
        f16x8 bf = *(const f16x8*)&Bsm[cur][ct * 16 + lr][ks * 32 + lk];
        acc[0][ct] = __builtin_amdgcn_mfma_f32_16x16x32_f16(af[0][ks], bf, acc[0][ct], 0, 0, 0);
        acc[1][ct] = __builtin_amdgcn_mfma_f32_16x16x32_f16(af[1][ks], bf, acc[1][ct], 0, 0, 0);
      }
    if (more) {
#pragma unroll
      for (int rt = 0; rt < 2; ++rt)
#pragma unroll
        for (int ks = 0; ks < 2; ++ks) {
          const float* vf = (const float*)areg[rt][ks];
#pragma unroll
          for (int q = 0; q < 8; ++q) af[rt][ks][q] = (_Float16)vf[q];
        }
#pragma unroll
      for (int q = 0; q < 4; ++q)
        *(f16x8*)&Bsm[cur ^ 1][bcol][bkh + q * 8] = breg[q];
    }
    __syncthreads();
  }

  // ---- epilogue: repack through LDS, coalesced fp16 stores ----
  _Float16* hb = &Bsm[0][0][0];           // reuse as [128][128] fp16 (needs 32 KB <= 36.9 KB)
  const int dcol = lane & 15;
  const int drow = (lane >> 4) * 4;
#pragma unroll
  for (int rt = 0; rt < 2; ++rt)
#pragma unroll
    for (int j = 0; j < 4; ++j) {
      int rl = wid * 32 + rt * 16 + drow + j;
#pragma unroll
      for (int ct = 0; ct < 8; ++ct)
        hb[rl * HID + ct * 16 + dcol] = (_Float16)acc[rt][ct][j];
    }
  __syncthreads();
#pragma unroll
  for (int q = 0; q < 8; ++q) {
    int f = t + 256 * q;                  // 0..2047: row = f>>4, seg = f&15
    int rowl = f >> 4, seg = f & 15;
    int grow = bm + rowl;
    if (grow < N_NODES)
      ((uint4*)(h16 + (size_t)grow * HID))[seg] = ((const uint4*)hb)[f];
  }
}

// ---------------- fused gather + self-loop + bias + relu + max-pool ----------------
// wave per 4 consecutive nodes; lane owns feature pair (2*lane, 2*lane+1):
// one 4-B packed-fp16 load per edge per lane.
__global__ __launch_bounds__(256) void k_gather(const _Float16* __restrict__ h16,
                                                const float* __restrict__ dinv,
                                                const int* __restrict__ start,
                                                const int2* __restrict__ ew,
                                                const float* __restrict__ b_conv,
                                                const int* __restrict__ batch,
                                                unsigned* __restrict__ pooled) {
  int gid = blockIdx.x * 256 + threadIdx.x;
  int wv = gid >> 6, lane = gid & 63;
  int n0 = wv * 4;
  if (n0 >= N_NODES) return;
  const unsigned* h32 = (const unsigned*)h16;   // h32[node*64 + lane]
  float bc0 = b_conv[2 * lane], bc1 = b_conv[2 * lane + 1];
  int gcur = -1;
  float m0 = 0.f, m1 = 0.f;
  int nend = n0 + 4 < N_NODES ? n0 + 4 : N_NODES;
  for (int i = n0; i < nend; ++i) {
    float di = dinv[i];
    float sw = di * di;
    float s0, s1;
    unpack16(h32[(size_t)i * 64 + lane], s0, s1);
    float a0 = s0 * sw, a1 = s1 * sw, p0 = 0.f, p1 = 0.f;
    int s = start[i], e = start[i + 1];
    for (int c = s; c < e; c += 64) {
      int cnt = e - c; if (cnt > 64) cnt = 64;
      int2 my = (lane < cnt) ? ew[c + lane] : make_int2(0, 0);
      int j = 0;
      for (; j + 1 < cnt; j += 2) {
        int e0 = __shfl(my.x, j), e1 = __shfl(my.x, j + 1);
        float w0 = __uint_as_float((unsigned)__shfl(my.y, j));
        float w1 = __uint_as_float((unsigned)__shfl(my.y, j + 1));
        unsigned u0 = h32[(size_t)e0 * 64 + lane];
        unsigned u1 = h32[(size_t)e1 * 64 + lane];
        float f00, f01, f10, f11;
        unpack16(u0, f00, f01); unpack16(u1, f10, f11);
        a0 = fmaf(f00, w0, a0); a1 = fmaf(f01, w0, a1);
        p0 = fmaf(f10, w1, p0); p1 = fmaf(f11, w1, p1);
      }
      if (j < cnt) {
        int e0 = __shfl(my.x, j);
        float w0 = __uint_as_float((unsigned)__shfl(my.y, j));
        unsigned u0 = h32[(size_t)e0 * 64 + lane];
        float f00, f01; unpack16(u0, f00, f01);
        a0 = fmaf(f00, w0, a0); a1 = fmaf(f01, w0, a1);
      }
    }
    a0 = fmaxf(a0 + p0 + bc0, 0.f);
    a1 = fmaxf(a1 + p1 + bc1, 0.f);
    int g = batch[i];
    if (g != gcur) {
      if (gcur >= 0) {
        atomicMax(&pooled[(size_t)gcur * HID + 2 * lane], __float_as_uint(m0));
        atomicMax(&pooled[(size_t)gcur * HID + 2 * lane + 1], __float_as_uint(m1));
      }
      gcur = g; m0 = a0; m1 = a1;
    } else {
      m0 = fmaxf(m0, a0);
      m1 = fmaxf(m1, a1);
    }
  }
  if (gcur >= 0) {
    atomicMax(&pooled[(size_t)gcur * HID + 2 * lane], __float_as_uint(m0));
    atomicMax(&pooled[(size_t)gcur * HID + 2 * lane + 1], __float_as_uint(m1));
  }
}

// ---------------- fused head: idx0 + news + hidden + logits + log_softmax ----------------
__global__ __launch_bounds__(128) void k_head(const float* __restrict__ x,
                                              const int* __restrict__ batch,
                                              const unsigned* __restrict__ pooled,
                                              const float* __restrict__ W0, const float* __restrict__ b0,
                                              const float* __restrict__ W1, const float* __restrict__ b1,
                                              const float* __restrict__ W2, const float* __restrict__ b2,
                                              float* __restrict__ out) {
  __shared__ float xr[IN_DIM];
  __shared__ float pl[HID];
  __shared__ float nn[HID];
  __shared__ float red[4];
  int g = blockIdx.x, t = threadIdx.x;
  // searchsorted(batch, g): first index with batch[idx] >= g
  int lo = 0, hi = N_NODES;
  while (lo < hi) {
    int mid = (lo + hi) >> 1;
    if (batch[mid] < g) lo = mid + 1; else hi = mid;
  }
  int i0 = lo < N_NODES ? lo : N_NODES - 1;
  const float* xp = x + (size_t)i0 * IN_DIM;
  for (int k = t; k < IN_DIM; k += 128) xr[k] = xp[k];
  pl[t] = __uint_as_float(pooled[(size_t)g * HID + t]);
  __syncthreads();
  float a = b0[t];
#pragma unroll 8
  for (int k = 0; k < IN_DIM; ++k) a = fmaf(xr[k], W0[(size_t)k * HID + t], a);
  nn[t] = fmaxf(a, 0.f);
  __syncthreads();
  float z = b1[t];
#pragma unroll 8
  for (int k = 0; k < HID; ++k) z = fmaf(pl[k], W1[(size_t)k * HID + t], z);
#pragma unroll 8
  for (int k = 0; k < HID; ++k) z = fmaf(nn[k], W1[(size_t)(HID + k) * HID + t], z);
  z = fmaxf(z, 0.f);
  float p0 = z * W2[2 * t], p1 = z * W2[2 * t + 1];
#pragma unroll
  for (int o = 32; o > 0; o >>= 1) {
    p0 += __shfl_down(p0, o);
    p1 += __shfl_down(p1, o);
  }
  if ((t & 63) == 0) { red[(t >> 6) * 2] = p0; red[(t >> 6) * 2 + 1] = p1; }
  __syncthreads();
  if (t == 0) {
    float l0 = b2[0] + red[0] + red[2];
    float l1 = b2[1] + red[1] + red[3];
    float m = fmaxf(l0, l1);
    float lse = m + logf(expf(l0 - m) + expf(l1 - m));
    out[g * 2 + 0] = l0 - lse;
    out[g * 2 + 1] = l1 - lse;
  }
}

extern "C" void kernel_launch(void* const* d_in, const int* in_sizes, int n_in,
                              void* d_out, int out_size, void* d_ws, size_t ws_size,
                              hipStream_t stream) {
  const float* x      = (const float*)d_in[0];
  const int* edge     = (const int*)d_in[1];
  const int* batch    = (const int*)d_in[2];
  const float* W_conv = (const float*)d_in[4];
  const float* b_conv = (const float*)d_in[5];
  const float* W0     = (const float*)d_in[6];
  const float* b0     = (const float*)d_in[7];
  const float* W1     = (const float*)d_in[8];
  const float* b1     = (const float*)d_in[9];
  const float* W2     = (const float*)d_in[10];
  const float* b2     = (const float*)d_in[11];
  float* out = (float*)d_out;

  const int* row = edge;
  const int* col = edge + N_EDGES;

  // workspace layout (bytes), 256B-aligned, total ~61.5 MB
  char* ws = (char*)d_ws;
  _Float16*  h16    = (_Float16*)(ws);                   //  51,200,000
  int*       deg    = (int*)  (ws + 51200000);           //     800,000
  float*     dinv   = (float*)(ws + 52000000);           //     800,000
  int*       start  = (int*)  (ws + 52800000);           //     800,004 (N+1)
  int*       cursor = (int*)  (ws + 53600256);           //     800,000
  int2*      ew     = (int2*) (ws + 54400256);           //   6,400,000
  int*       bsum   = (int*)  (ws + 60800256);           //         784
  int*       boff   = (int*)  (ws + 60801280);           //         784
  _Float16*  WT     = (_Float16*)(ws + 60802304);        //     196,608
  unsigned*  pooled = (unsigned*)(ws + 60998912);        //     524,288

  hipMemsetAsync(deg, 0, (size_t)N_NODES * sizeof(int), stream);
  hipMemsetAsync(pooled, 0, (size_t)NG * HID * sizeof(unsigned), stream);

  k_deg<<<(N_EDGES + 255) / 256, 256, 0, stream>>>(col, deg);
  k_scan1<<<NSB, 256, 0, stream>>>(deg, bsum);
  k_scan2<<<1, 256, 0, stream>>>(bsum, boff);
  k_scan3<<<NSB, 256, 0, stream>>>(deg, boff, start, cursor, dinv);
  k_bin<<<(N_EDGES + 255) / 256, 256, 0, stream>>>(row, col, dinv, cursor, ew);
  k_prepW<<<(IN_DIM * HID + 255) / 256, 256, 0, stream>>>(W_conv, WT);
  k_gemm_mfma<<<(N_NODES + BM - 1) / BM, 256, 0, stream>>>(x, WT, h16);
  k_gather<<<((N_NODES + 3) / 4 * 64 + 255) / 256, 256, 0, stream>>>(h16, dinv, start, ew, b_conv, batch, pooled);
  k_head<<<NG, 128, 0, stream>>>(x, batch, pooled, W0, b0, W1, b1, W2, b2, out);
}

// Round 7
// 406.151 us; speedup vs baseline: 2.6112x; 1.0228x over previous
//
#include <hip/hip_runtime.h>

#define N_NODES 200000
#define N_EDGES 800000
#define IN_DIM 768
#define HID 128
#define NG 1024

// MFMA GEMM tile: BM=128, BK=32, 24 K-tiles, double-buffered LDS via global_load_lds
#define BM 128
#define BKT 32
#define NT (IN_DIM / BKT)     // 24

// scan
#define SCAN_B 1024
#define NSB ((N_NODES + SCAN_B - 1) / SCAN_B)   // 196

typedef _Float16 f16x8 __attribute__((ext_vector_type(8)));
typedef float f32x4 __attribute__((ext_vector_type(4)));

__device__ __forceinline__ void gload_lds16(const void* g, void* l) {
  __builtin_amdgcn_global_load_lds((const __attribute__((address_space(1))) void*)g,
                                   (__attribute__((address_space(3))) void*)l, 16, 0, 0);
}

__device__ inline void unpack16(unsigned u, float& a, float& b) {
  union { unsigned v; _Float16 f[2]; } c; c.v = u;
  a = (float)c.f[0]; b = (float)c.f[1];
}

// ---------------- degree + W-transpose (independent work, one launch) ----------------
__global__ __launch_bounds__(256) void k_deg_prepW(const int* __restrict__ col, int* __restrict__ deg,
                                                   const float* __restrict__ W, _Float16* __restrict__ WT) {
  int gid = blockIdx.x * 256 + threadIdx.x;
  if (gid < N_EDGES) atomicAdd(&deg[col[gid]], 1);
  if (gid < IN_DIM * HID) {
    int k = gid / HID, n = gid % HID;
    WT[(size_t)n * IN_DIM + k] = (_Float16)W[gid];
  }
}

// ---------------- exclusive scan of deg -> start/cursor (+dinv fused) ----------------
__global__ __launch_bounds__(256) void k_scan1(const int* __restrict__ deg, int* __restrict__ bsum) {
  __shared__ int red[256];
  int b = blockIdx.x, t = threadIdx.x;
  int base = b * SCAN_B + t * 4;
  int s = 0;
#pragma unroll
  for (int q = 0; q < 4; ++q) { int idx = base + q; if (idx < N_NODES) s += deg[idx]; }
  red[t] = s; __syncthreads();
  for (int o = 128; o > 0; o >>= 1) { if (t < o) red[t] += red[t + o]; __syncthreads(); }
  if (t == 0) bsum[b] = red[0];
}

__global__ __launch_bounds__(256) void k_scan2(const int* __restrict__ bsum, int* __restrict__ boff) {
  __shared__ int s[256];
  int t = threadIdx.x;
  int v = (t < NSB) ? bsum[t] : 0;
  s[t] = v; __syncthreads();
  for (int o = 1; o < 256; o <<= 1) {
    int add = (t >= o) ? s[t - o] : 0;
    __syncthreads();
    s[t] += add;
    __syncthreads();
  }
  if (t < NSB) boff[t] = s[t] - v;  // exclusive
}

__global__ __launch_bounds__(256) void k_scan3(const int* __restrict__ deg, const int* __restrict__ boff,
                                               int* __restrict__ start, int* __restrict__ cursor,
                                               float* __restrict__ dinv) {
  __shared__ int s[256];
  int b = blockIdx.x, t = threadIdx.x;
  int base = b * SCAN_B + t * 4;
  int v[4]; int sum = 0;
#pragma unroll
  for (int q = 0; q < 4; ++q) { v[q] = (base + q < N_NODES) ? deg[base + q] : 0; sum += v[q]; }
  s[t] = sum; __syncthreads();
  int my = sum;
  for (int o = 1; o < 256; o <<= 1) {
    int add = (t >= o) ? s[t - o] : 0;
    __syncthreads();
    s[t] += add;
    __syncthreads();
  }
  int excl = s[t] - my + boff[b];
#pragma unroll
  for (int q = 0; q < 4; ++q) {
    int idx = base + q;
    if (idx < N_NODES) {
      start[idx] = excl; cursor[idx] = excl; excl += v[q];
      dinv[idx] = rsqrtf((float)(v[q] + 1));   // +1 self loop
    }
  }
  if (b == 0 && t == 0) start[N_NODES] = N_EDGES;
}

// ---------------- bin edges into CSR with precomputed weights ----------------
__global__ __launch_bounds__(256) void k_bin(const int* __restrict__ row, const int* __restrict__ col,
                                             const float* __restrict__ dinv,
                                             int* __restrict__ cursor, int2* __restrict__ ew) {
  int e = blockIdx.x * 256 + threadIdx.x;
  if (e < N_EDGES) {
    int r = row[e], c = col[e];
    int slot = atomicAdd(&cursor[c], 1);
    float w = dinv[r] * dinv[c];
    ew[slot] = make_int2(r, __float_as_int(w));
  }
}

// ---------------- h16 = fp16(x @ W_conv) : gload_lds-staged, XOR-swizzled, dbuf ----------------
// LDS arena: A dbuf 2x16KB (fp32 [128][32], swz slot^=(row&7) in 16B units of 128B rows)
//            B dbuf 2x8KB  (fp16 [128][32], swz slot^=((row>>1)&3) in 16B units of 64B rows)
__global__ __launch_bounds__(256, 3) void k_gemm_mfma(const float* __restrict__ x,
                                                      const _Float16* __restrict__ WT,
                                                      _Float16* __restrict__ h16) {
  __shared__ __align__(16) char arena[49152];   // 48 KB

  const int t = threadIdx.x;
  const int lane = t & 63;
  const int wid = t >> 6;                 // wave 0..3
  const int bm = blockIdx.x * BM;

  f32x4 acc[2][8];
#pragma unroll
  for (int i = 0; i < 2; ++i)
#pragma unroll
    for (int j = 0; j < 8; ++j) acc[i][j] = (f32x4){0.f, 0.f, 0.f, 0.f};

  const int lr = lane & 15;               // A row / B col within 16-tile
  const int s0 = (lane >> 4) * 2;         // A k-slot base (16B units): 0,2,4,6
  const int bslot_r = lane >> 4;          // B k-slot: 0..3

  // staging constants (per-lane, loop-invariant)
  const int a_srow = lane >> 3;           // 0..7  (row within wave's 8-row pass)
  const int a_scol = ((lane & 7) ^ (lane >> 3)) * 4;   // swizzled f32 col chunk
  const int b_srow = lane >> 2;           // 0..15
  const int b_scol = (((lane & 3) ^ ((lane >> 3) & 3)) * 8); // swizzled f16 col chunk

  // main loop staging issues tile tt+1 into buf cur^1
  auto stage = [&](int k0, int dbuf) {
    char* bA = arena + dbuf * 16384;
    char* bB = arena + 32768 + dbuf * 8192;
#pragma unroll
    for (int p = 0; p < 4; ++p) {
      int r = p * 32 + wid * 8 + a_srow;
      int grow = bm + r; if (grow >= N_NODES) grow = N_NODES - 1;
      gload_lds16(x + (size_t)grow * IN_DIM + k0 + a_scol, bA + p * 4096 + wid * 1024);
    }
#pragma unroll
    for (int p = 0; p < 2; ++p) {
      int r = p * 64 + wid * 16 + b_srow;
      gload_lds16(WT + (size_t)r * IN_DIM + k0 + b_scol, bB + p * 4096 + wid * 1024);
    }
  };

  stage(0, 0);
  __syncthreads();   // drains vmcnt(0): tile 0 staged

  for (int tt = 0; tt < NT; ++tt) {
    const int cur = tt & 1;
    if (tt + 1 < NT) stage((tt + 1) * BKT, cur ^ 1);

    const char* bA = arena + cur * 16384;
    const char* bB = arena + 32768 + cur * 8192;

    f16x8 af[2];
#pragma unroll
    for (int rt = 0; rt < 2; ++rt) {
      int r = wid * 32 + rt * 16 + lr;
      const char* rb = bA + r * 128;
      int f = r & 7;
      float4 lo = *(const float4*)(rb + ((s0 ^ f) << 4));
      float4 hi = *(const float4*)(rb + (((s0 + 1) ^ f) << 4));
      af[rt][0] = (_Float16)lo.x; af[rt][1] = (_Float16)lo.y;
      af[rt][2] = (_Float16)lo.z; af[rt][3] = (_Float16)lo.w;
      af[rt][4] = (_Float16)hi.x; af[rt][5] = (_Float16)hi.y;
      af[rt][6] = (_Float16)hi.z; af[rt][7] = (_Float16)hi.w;
    }
#pragma unroll
    for (int ct = 0; ct < 8; ++ct) {
      int cr = ct * 16 + lr;
      f16x8 bf = *(const f16x8*)(bB + cr * 64 + ((bslot_r ^ ((cr >> 1) & 3)) << 4));
      acc[0][ct] = __builtin_amdgcn_mfma_f32_16x16x32_f16(af[0], bf, acc[0][ct], 0, 0, 0);
      acc[1][ct] = __builtin_amdgcn_mfma_f32_16x16x32_f16(af[1], bf, acc[1][ct], 0, 0, 0);
    }
    __syncthreads();  // drains: tile tt+1 loads landed; all waves done reading buf cur
  }

  // ---- epilogue: repack through LDS (reuse arena), coalesced fp16 stores ----
  _Float16* hb = (_Float16*)arena;        // [128][128] fp16 = 32 KB
  const int dcol = lane & 15;
  const int drow = (lane >> 4) * 4;
#pragma unroll
  for (int rt = 0; rt < 2; ++rt)
#pragma unroll
    for (int j = 0; j < 4; ++j) {
      int rl = wid * 32 + rt * 16 + drow + j;
#pragma unroll
      for (int ct = 0; ct < 8; ++ct)
        hb[rl * HID + ct * 16 + dcol] = (_Float16)acc[rt][ct][j];
    }
  __syncthreads();
#pragma unroll
  for (int q = 0; q < 8; ++q) {
    int f = t + 256 * q;                  // 0..2047: row = f>>4, seg = f&15
    int rowl = f >> 4, seg = f & 15;
    int grow = bm + rowl;
    if (grow < N_NODES)
      ((uint4*)(h16 + (size_t)grow * HID))[seg] = ((const uint4*)hb)[f];
  }
}

// ---------------- fused gather + self-loop + bias + relu + max-pool ----------------
// wave per 2 consecutive nodes (2x waves vs R6 for latency hiding);
// lane owns feature pair (2*lane, 2*lane+1): one 4-B packed-fp16 load per edge per lane.
__global__ __launch_bounds__(256) void k_gather(const _Float16* __restrict__ h16,
                                                const float* __restrict__ dinv,
                                                const int* __restrict__ start,
                                                const int2* __restrict__ ew,
                                                const float* __restrict__ b_conv,
                                                const int* __restrict__ batch,
                                                unsigned* __restrict__ pooled) {
  int gid = blockIdx.x * 256 + threadIdx.x;
  int wv = gid >> 6, lane = gid & 63;
  int n0 = wv * 2;
  if (n0 >= N_NODES) return;
  const unsigned* h32 = (const unsigned*)h16;   // h32[node*64 + lane]
  float bc0 = b_conv[2 * lane], bc1 = b_conv[2 * lane + 1];
  int gcur = -1;
  float m0 = 0.f, m1 = 0.f;
  int nend = n0 + 2 < N_NODES ? n0 + 2 : N_NODES;
  for (int i = n0; i < nend; ++i) {
    float di = dinv[i];
    float sw = di * di;
    float s0, s1;
    unpack16(h32[(size_t)i * 64 + lane], s0, s1);
    float a0 = s0 * sw, a1 = s1 * sw, p0 = 0.f, p1 = 0.f;
    int s = start[i], e = start[i + 1];
    for (int c = s; c < e; c += 64) {
      int cnt = e - c; if (cnt > 64) cnt = 64;
      int2 my = (lane < cnt) ? ew[c + lane] : make_int2(0, 0);
      int j = 0;
      for (; j + 1 < cnt; j += 2) {
        int e0 = __shfl(my.x, j), e1 = __shfl(my.x, j + 1);
        float w0 = __uint_as_float((unsigned)__shfl(my.y, j));
        float w1 = __uint_as_float((unsigned)__shfl(my.y, j + 1));
        unsigned u0 = h32[(size_t)e0 * 64 + lane];
        unsigned u1 = h32[(size_t)e1 * 64 + lane];
        float f00, f01, f10, f11;
        unpack16(u0, f00, f01); unpack16(u1, f10, f11);
        a0 = fmaf(f00, w0, a0); a1 = fmaf(f01, w0, a1);
        p0 = fmaf(f10, w1, p0); p1 = fmaf(f11, w1, p1);
      }
      if (j < cnt) {
        int e0 = __shfl(my.x, j);
        float w0 = __uint_as_float((unsigned)__shfl(my.y, j));
        unsigned u0 = h32[(size_t)e0 * 64 + lane];
        float f00, f01; unpack16(u0, f00, f01);
        a0 = fmaf(f00, w0, a0); a1 = fmaf(f01, w0, a1);
      }
    }
    a0 = fmaxf(a0 + p0 + bc0, 0.f);
    a1 = fmaxf(a1 + p1 + bc1, 0.f);
    int g = batch[i];
    if (g != gcur) {
      if (gcur >= 0) {
        atomicMax(&pooled[(size_t)gcur * HID + 2 * lane], __float_as_uint(m0));
        atomicMax(&pooled[(size_t)gcur * HID + 2 * lane + 1], __float_as_uint(m1));
      }
      gcur = g; m0 = a0; m1 = a1;
    } else {
      m0 = fmaxf(m0, a0);
      m1 = fmaxf(m1, a1);
    }
  }
  if (gcur >= 0) {
    atomicMax(&pooled[(size_t)gcur * HID + 2 * lane], __float_as_uint(m0));
    atomicMax(&pooled[(size_t)gcur * HID + 2 * lane + 1], __float_as_uint(m1));
  }
}

// ---------------- fused head: idx0 + news + hidden + logits + log_softmax ----------------
__global__ __launch_bounds__(128) void k_head(const float* __restrict__ x,
                                              const int* __restrict__ batch,
                                              const unsigned* __restrict__ pooled,
                                              const float* __restrict__ W0, const float* __restrict__ b0,
                                              const float* __restrict__ W1, const float* __restrict__ b1,
                                              const float* __restrict__ W2, const float* __restrict__ b2,
                                              float* __restrict__ out) {
  __shared__ float xr[IN_DIM];
  __shared__ float pl[HID];
  __shared__ float nn[HID];
  __shared__ float red[4];
  int g = blockIdx.x, t = threadIdx.x;
  int lo = 0, hi = N_NODES;
  while (lo < hi) {
    int mid = (lo + hi) >> 1;
    if (batch[mid] < g) lo = mid + 1; else hi = mid;
  }
  int i0 = lo < N_NODES ? lo : N_NODES - 1;
  const float* xp = x + (size_t)i0 * IN_DIM;
  for (int k = t; k < IN_DIM; k += 128) xr[k] = xp[k];
  pl[t] = __uint_as_float(pooled[(size_t)g * HID + t]);
  __syncthreads();
  float a = b0[t];
#pragma unroll 8
  for (int k = 0; k < IN_DIM; ++k) a = fmaf(xr[k], W0[(size_t)k * HID + t], a);
  nn[t] = fmaxf(a, 0.f);
  __syncthreads();
  float z = b1[t];
#pragma unroll 8
  for (int k = 0; k < HID; ++k) z = fmaf(pl[k], W1[(size_t)k * HID + t], z);
#pragma unroll 8
  for (int k = 0; k < HID; ++k) z = fmaf(nn[k], W1[(size_t)(HID + k) * HID + t], z);
  z = fmaxf(z, 0.f);
  float p0 = z * W2[2 * t], p1 = z * W2[2 * t + 1];
#pragma unroll
  for (int o = 32; o > 0; o >>= 1) {
    p0 += __shfl_down(p0, o);
    p1 += __shfl_down(p1, o);
  }
  if ((t & 63) == 0) { red[(t >> 6) * 2] = p0; red[(t >> 6) * 2 + 1] = p1; }
  __syncthreads();
  if (t == 0) {
    float l0 = b2[0] + red[0] + red[2];
    float l1 = b2[1] + red[1] + red[3];
    float m = fmaxf(l0, l1);
    float lse = m + logf(expf(l0 - m) + expf(l1 - m));
    out[g * 2 + 0] = l0 - lse;
    out[g * 2 + 1] = l1 - lse;
  }
}

extern "C" void kernel_launch(void* const* d_in, const int* in_sizes, int n_in,
                              void* d_out, int out_size, void* d_ws, size_t ws_size,
                              hipStream_t stream) {
  const float* x      = (const float*)d_in[0];
  const int* edge     = (const int*)d_in[1];
  const int* batch    = (const int*)d_in[2];
  const float* W_conv = (const float*)d_in[4];
  const float* b_conv = (const float*)d_in[5];
  const float* W0     = (const float*)d_in[6];
  const float* b0     = (const float*)d_in[7];
  const float* W1     = (const float*)d_in[8];
  const float* b1     = (const float*)d_in[9];
  const float* W2     = (const float*)d_in[10];
  const float* b2     = (const float*)d_in[11];
  float* out = (float*)d_out;

  const int* row = edge;
  const int* col = edge + N_EDGES;

  // workspace layout (bytes); deg+pooled adjacent for a single memset
  char* ws = (char*)d_ws;
  _Float16*  h16    = (_Float16*)(ws);                   //  51,200,000
  int*       deg    = (int*)  (ws + 51200000);           //     800,000
  unsigned*  pooled = (unsigned*)(ws + 52000000);        //     524,288
  float*     dinv   = (float*)(ws + 52524288);           //     800,000
  int*       start  = (int*)  (ws + 53324288);           //     800,256 (N+1)
  int*       cursor = (int*)  (ws + 54124544);           //     800,000
  int2*      ew     = (int2*) (ws + 54924544);           //   6,400,000
  int*       bsum   = (int*)  (ws + 61324544);           //       1,024
  int*       boff   = (int*)  (ws + 61325568);           //       1,024
  _Float16*  WT     = (_Float16*)(ws + 61326592);        //     196,608

  hipMemsetAsync(deg, 0, 1324288, stream);  // deg (800,000) + pooled (524,288), adjacent

  k_deg_prepW<<<(N_EDGES + 255) / 256, 256, 0, stream>>>(col, deg, W_conv, WT);
  k_scan1<<<NSB, 256, 0, stream>>>(deg, bsum);
  k_scan2<<<1, 256, 0, stream>>>(bsum, boff);
  k_scan3<<<NSB, 256, 0, stream>>>(deg, boff, start, cursor, dinv);
  k_bin<<<(N_EDGES + 255) / 256, 256, 0, stream>>>(row, col, dinv, cursor, ew);
  k_gemm_mfma<<<(N_NODES + BM - 1) / BM, 256, 0, stream>>>(x, WT, h16);
  k_gather<<<(((N_NODES + 1) / 2) * 64 + 255) / 256, 256, 0, stream>>>(h16, dinv, start, ew, b_conv, batch, pooled);
  k_head<<<NG, 128, 0, stream>>>(x, batch, pooled, W0, b0, W1, b1, W2, b2, out);
}